// Round 8
// baseline (497.597 us; speedup 1.0000x reference)
//
#include <hip/hip_runtime.h>

// EntityClassify (R-GCN) — round 8.
// r7 post-mortem: embedded-count records REGRESSED (atomic+store don't merge
// — 51MB record array not L2-resident between touches; pull header reads got
// 4x worse; memset 32x). Reverted to r6 layout (compact cursor + csr_pad).
// r6 flaw found: dedicated fill blocks reserved 48KB LDS unused -> 3/CU cap
// on in-flight atomics. Fix: in-block fusion — every gemm block first issues
// its 2048 fill edges (4 chains/thread), then its gemm tile; atomics drain
// under LDS staging + MFMA. Grid 7813 -> 1563. H1(concurrency-bound): fused1
// ~150-180us. H2(TCC-rate-bound): unchanged ~230 -> fill is at floor.

constexpr int NN = 100000, RR = 4, EE = 800000;
constexpr int RN = RR * NN;
constexpr int RE = RR * EE;
constexpr int CAP = 32;
constexpr int NG1 = (NN + 63) / 64;     // 1563 tiles; also ceil(RE/2048)=1563

typedef short bf16x8 __attribute__((ext_vector_type(8)));
typedef float f32x4 __attribute__((ext_vector_type(4)));

__device__ inline unsigned short f2bf(float f) {
  unsigned u = __float_as_uint(f);
  u += 0x7FFF + ((u >> 16) & 1);
  return (unsigned short)(u >> 16);
}
__device__ inline float bf2f(unsigned short s) {
  return __uint_as_float(((unsigned)s) << 16);
}

// ---- weights -> bf16 [n][k]: BT1 [320][256], BT2 [80][64] ----
__global__ __launch_bounds__(256) void prep_w_kernel(const float* __restrict__ W1,
                                                     const float* __restrict__ L1w,
                                                     const float* __restrict__ W2,
                                                     const float* __restrict__ L2w,
                                                     unsigned short* __restrict__ BT1,
                                                     unsigned short* __restrict__ BT2) {
  int idx = blockIdx.x * 256 + threadIdx.x;
  if (idx < 320 * 256) {
    int n = idx >> 8, k = idx & 255;
    float v = (n < 256) ? W1[((size_t)((n >> 6) * 256 + k)) * 64 + (n & 63)]
                        : L1w[(size_t)k * 64 + (n - 256)];
    BT1[idx] = f2bf(v);
  } else {
    int j = idx - 320 * 256;
    if (j < 80 * 64) {
      int n = j >> 6, k = j & 63;
      float v = (n < 64) ? W2[((size_t)((n >> 4) * 64 + k)) * 16 + (n & 15)]
                         : L2w[(size_t)k * 16 + (n - 64)];
      BT2[j] = f2bf(v);
    }
  }
}

// ---- fused1: per block, 2048 fill edges THEN one gemm1 M-tile ----
__global__ __launch_bounds__(512) void fused1_kernel(const float* __restrict__ x,
                                                     const unsigned short* __restrict__ BT1,
                                                     const float* __restrict__ L1b,
                                                     const int* __restrict__ src,
                                                     const int* __restrict__ dst,
                                                     int* __restrict__ cursor,
                                                     int* __restrict__ csr_pad,
                                                     unsigned short* __restrict__ hwcat,
                                                     float* __restrict__ h) {
  __shared__ char Al[64 * 64 * 2];    // 8 KB
  __shared__ char Bl[320 * 64 * 2];   // 40 KB
  const int bid = blockIdx.x;
  const int t = threadIdx.x;

  // ---- fill phase: 4 independent atomic->store chains per thread ----
  {
    int e0 = bid * 2048 + t;
#pragma unroll
    for (int i = 0; i < 4; ++i) {
      int fl = e0 + 512 * i;
      if (fl < RE) {
        int r = (unsigned)fl / (unsigned)EE;
        int idx = dst[fl] * RR + r;           // [v][r] compact layout
        int pos = atomicAdd(&cursor[idx], 1);
        if (pos < CAP) csr_pad[(size_t)idx * CAP + pos] = src[fl];
      }
    }
  }

  // ---- gemm phase: M-tile 64, N=320, K=256 ----
  const int m0 = bid * 64;
  const int wid = t >> 6, lane = t & 63;
  const int wm = wid >> 2, wn = wid & 3;   // 2 x 4 wave grid
  const int l15 = lane & 15, g = lane >> 4;

  f32x4 acc[2][5];
#pragma unroll
  for (int i = 0; i < 2; ++i)
#pragma unroll
    for (int j = 0; j < 5; ++j) acc[i][j] = (f32x4){0.f, 0.f, 0.f, 0.f};

  for (int kc = 0; kc < 4; ++kc) {
    if (kc) __syncthreads();
#pragma unroll
    for (int it = 0; it < 2; ++it) {
      int fl = t + 512 * it;
      int row = fl >> 4, kq = (fl & 15) * 4;
      int rg = m0 + row;
      float4 v = (rg < NN) ? *(const float4*)(x + (size_t)rg * 256 + kc * 64 + kq)
                           : make_float4(0.f, 0.f, 0.f, 0.f);
      ushort4 pck = {f2bf(v.x), f2bf(v.y), f2bf(v.z), f2bf(v.w)};
      int wb = ((row * 64 + kq) * 2) ^ ((row & 7) << 4);
      *(ushort4*)(Al + wb) = pck;
    }
#pragma unroll
    for (int it = 0; it < 5; ++it) {
      int fl = t + 512 * it;
      int n = fl >> 3, i8 = (fl & 7) * 8;
      uint4 u = *(const uint4*)(BT1 + (size_t)n * 256 + kc * 64 + i8);
      int wb = ((n * 64 + i8) * 2) ^ ((n & 7) << 4);
      *(uint4*)(Bl + wb) = u;
    }
    __syncthreads();
#pragma unroll
    for (int ks = 0; ks < 2; ++ks) {
      bf16x8 af[2], bfr[5];
#pragma unroll
      for (int mi = 0; mi < 2; ++mi) {
        int row = wm * 32 + mi * 16 + l15;
        int byte = ((row * 64 + ks * 32 + g * 8) * 2) ^ ((row & 7) << 4);
        af[mi] = *(const bf16x8*)(Al + byte);
      }
#pragma unroll
      for (int ni = 0; ni < 5; ++ni) {
        int n = wn * 80 + ni * 16 + l15;
        int byte = ((n * 64 + ks * 32 + g * 8) * 2) ^ ((n & 7) << 4);
        bfr[ni] = *(const bf16x8*)(Bl + byte);
      }
#pragma unroll
      for (int mi = 0; mi < 2; ++mi)
#pragma unroll
        for (int ni = 0; ni < 5; ++ni)
          acc[mi][ni] = __builtin_amdgcn_mfma_f32_16x16x32_bf16(af[mi], bfr[ni], acc[mi][ni], 0, 0, 0);
    }
  }
#pragma unroll
  for (int mi = 0; mi < 2; ++mi) {
    int rbase = m0 + wm * 32 + mi * 16 + 4 * g;
#pragma unroll
    for (int ni = 0; ni < 5; ++ni) {
      int n0 = wn * 80 + ni * 16;
      int n = n0 + l15;
#pragma unroll
      for (int e = 0; e < 4; ++e) {
        int row = rbase + e;
        if (row >= NN) continue;
        float v = acc[mi][ni][e];
        if (n0 < 256) hwcat[(size_t)row * 256 + n] = f2bf(v);
        else h[(size_t)row * 64 + (n - 256)] = v + L1b[n - 256];
      }
    }
  }
}

// ---- pullgemm2: M-tile 64, 256 threads; relation-interleaved gather ----
__global__ __launch_bounds__(256) void pullgemm2_kernel(const float* __restrict__ h,
                                                        const unsigned short* __restrict__ hwcat,
                                                        const int* __restrict__ csr_pad,
                                                        const int* __restrict__ cursor,
                                                        const unsigned short* __restrict__ BT2,
                                                        const float* __restrict__ L2b,
                                                        unsigned short* __restrict__ hw2,
                                                        float* __restrict__ out) {
  __shared__ char Al[64 * 64 * 2];   // 8 KB
  __shared__ char Bl[80 * 64 * 2];   // 10 KB
  const int t = threadIdx.x;
  const int m0 = blockIdx.x * 64;
  const int wid = t >> 6, lane = t & 63;
  const int l15 = lane & 15, g = lane >> 4;

  for (int i = 0; i < 16; ++i) {
    int row = wid * 16 + i;
    int v = m0 + row;
    float hval = 0.f;
    if (v < NN) {
      hval = h[(size_t)v * 64 + lane];
      int4 dg = *(const int4*)(cursor + v * 4);
      const int* lst = csr_pad + (size_t)v * (RR * CAP);
      int dd0 = dg.x < CAP ? dg.x : CAP, dd1 = dg.y < CAP ? dg.y : CAP;
      int dd2 = dg.z < CAP ? dg.z : CAP, dd3 = dg.w < CAP ? dg.w : CAP;
      float w0 = 1.0f / (float)(dg.x > 1 ? dg.x : 1);
      float w1 = 1.0f / (float)(dg.y > 1 ? dg.y : 1);
      float w2 = 1.0f / (float)(dg.z > 1 ? dg.z : 1);
      float w3 = 1.0f / (float)(dg.w > 1 ? dg.w : 1);
      int dmax = dd0 > dd1 ? dd0 : dd1;
      dmax = dmax > dd2 ? dmax : dd2;
      dmax = dmax > dd3 ? dmax : dd3;
      float a0 = 0.f, a1 = 0.f, a2 = 0.f, a3 = 0.f;
#pragma unroll 8
      for (int j = 0; j < dmax; ++j) {
        int e0 = lst[0 * CAP + j], e1 = lst[1 * CAP + j];
        int e2 = lst[2 * CAP + j], e3 = lst[3 * CAP + j];
        int s0 = (j < dd0) ? e0 : 0, s1 = (j < dd1) ? e1 : 0;
        int s2 = (j < dd2) ? e2 : 0, s3 = (j < dd3) ? e3 : 0;
        float f0 = bf2f(hwcat[(size_t)s0 * 256 + 0 * 64 + lane]);
        float f1 = bf2f(hwcat[(size_t)s1 * 256 + 1 * 64 + lane]);
        float f2 = bf2f(hwcat[(size_t)s2 * 256 + 2 * 64 + lane]);
        float f3 = bf2f(hwcat[(size_t)s3 * 256 + 3 * 64 + lane]);
        a0 += (j < dd0) ? f0 : 0.f;
        a1 += (j < dd1) ? f1 : 0.f;
        a2 += (j < dd2) ? f2 : 0.f;
        a3 += (j < dd3) ? f3 : 0.f;
      }
      hval += a0 * w0 + a1 * w1 + a2 * w2 + a3 * w3;
      hval = fmaxf(hval, 0.f);
    }
    int wb = ((row * 64 + lane) * 2) ^ ((row & 7) << 4);
    *(unsigned short*)(Al + wb) = f2bf(hval);
  }
  // stage B: 80 x 64 bf16 = 640 uint4
#pragma unroll
  for (int it = 0; it < 3; ++it) {
    int fl = t + 256 * it;
    if (fl < 640) {
      int n = fl >> 3, i8 = (fl & 7) * 8;
      uint4 u = *(const uint4*)(BT2 + (size_t)n * 64 + i8);
      int wb = ((n * 64 + i8) * 2) ^ ((n & 7) << 4);
      *(uint4*)(Bl + wb) = u;
    }
  }
  __syncthreads();

  f32x4 acc[5];
#pragma unroll
  for (int j = 0; j < 5; ++j) acc[j] = (f32x4){0.f, 0.f, 0.f, 0.f};
#pragma unroll
  for (int ks = 0; ks < 2; ++ks) {
    bf16x8 af, bfr[5];
    {
      int row = wid * 16 + l15;
      int byte = ((row * 64 + ks * 32 + g * 8) * 2) ^ ((row & 7) << 4);
      af = *(const bf16x8*)(Al + byte);
    }
#pragma unroll
    for (int ni = 0; ni < 5; ++ni) {
      int n = ni * 16 + l15;
      int byte = ((n * 64 + ks * 32 + g * 8) * 2) ^ ((n & 7) << 4);
      bfr[ni] = *(const bf16x8*)(Bl + byte);
    }
#pragma unroll
    for (int ni = 0; ni < 5; ++ni)
      acc[ni] = __builtin_amdgcn_mfma_f32_16x16x32_bf16(af, bfr[ni], acc[ni], 0, 0, 0);
  }
  int rbase = m0 + wid * 16 + 4 * g;
#pragma unroll
  for (int ni = 0; ni < 5; ++ni) {
    int n0 = ni * 16;
    int n = n0 + l15;
#pragma unroll
    for (int e = 0; e < 4; ++e) {
      int row = rbase + e;
      if (row >= NN) continue;
      float v = acc[ni][e];
      if (n0 < 64) hw2[(size_t)row * 64 + n] = f2bf(v);
      else out[(size_t)row * 16 + (n - 64)] = v + L2b[n - 64];
    }
  }
}

// ---- pull layer2: lane-group = relation; 4 concurrent lists ----
__global__ __launch_bounds__(256) void pull16_kernel(const unsigned short* __restrict__ hw2,
                                                     const int* __restrict__ csr_pad,
                                                     const int* __restrict__ cursor,
                                                     float* __restrict__ out) {
  int v = blockIdx.x * 4 + (threadIdx.x >> 6);
  if (v >= NN) return;
  int lane = threadIdx.x & 63;
  int c = lane & 15, g = lane >> 4;   // g = relation
  int degg = cursor[v * 4 + g];
  int dd = degg < CAP ? degg : CAP;
  float w = 1.0f / (float)(degg > 1 ? degg : 1);
  const int* lst = csr_pad + (size_t)v * (RR * CAP) + g * CAP;
  float a = 0.f;
#pragma unroll 8
  for (int j = 0; j < dd; ++j) {
    int s = lst[j];
    a += bf2f(hw2[(size_t)s * 64 + g * 16 + c]);
  }
  a *= w;
  a += __shfl_xor(a, 16);
  a += __shfl_xor(a, 32);
  if (lane < 16) out[(size_t)v * 16 + lane] += a;
}

extern "C" void kernel_launch(void* const* d_in, const int* in_sizes, int n_in,
                              void* d_out, int out_size, void* d_ws, size_t ws_size,
                              hipStream_t stream) {
  const float* x   = (const float*)d_in[0];
  const int*   src = (const int*)d_in[1];
  const int*   dst = (const int*)d_in[2];
  const float* W1  = (const float*)d_in[3];
  const float* L1w = (const float*)d_in[4];
  const float* L1b = (const float*)d_in[5];
  const float* W2  = (const float*)d_in[6];
  const float* L2w = (const float*)d_in[7];
  const float* L2b = (const float*)d_in[8];
  float* out = (float*)d_out;

  char* p = (char*)d_ws;
  int* csr_pad = (int*)p;                     p += (size_t)RN * CAP * 4;      // 51.2 MB
  int* cursor  = (int*)p;                     p += (size_t)RN * 4;            // 1.6 MB
  unsigned short* hwcat = (unsigned short*)p; p += (size_t)NN * 256 * 2;      // 51.2 MB
  float* h = (float*)p;                       p += (size_t)NN * 64 * 4;       // 25.6 MB
  unsigned short* hw2 = (unsigned short*)p;   p += (size_t)NN * 64 * 2;       // 12.8 MB
  unsigned short* BT1 = (unsigned short*)p;   p += 320 * 256 * 2;
  unsigned short* BT2 = (unsigned short*)p;   p += 80 * 64 * 2;
  if ((size_t)(p - (char*)d_ws) > ws_size) return;  // visible fail (poison stays)

  hipMemsetAsync(cursor, 0, (size_t)RN * 4, stream);
  prep_w_kernel<<<(320 * 256 + 80 * 64 + 255) / 256, 256, 0, stream>>>(W1, L1w, W2, L2w, BT1, BT2);
  fused1_kernel<<<NG1, 512, 0, stream>>>(x, BT1, L1b, src, dst, cursor, csr_pad, hwcat, h);
  pullgemm2_kernel<<<(NN + 63) / 64, 256, 0, stream>>>(h, hwcat, csr_pad, cursor, BT2, L2b, hw2, out);
  pull16_kernel<<<(NN + 3) / 4, 256, 0, stream>>>(hw2, csr_pad, cursor, out);
}

// Round 9
// 396.311 us; speedup vs baseline: 1.2556x; 1.2556x over previous
//
#include <hip/hip_runtime.h>

// EntityClassify (R-GCN) — round 9.
// r8 post-mortem: in-block fill->gemm phasing REGRESSED (phases run back-to-
// back chip-wide; no cross-phase overlap). Lesson: overlap needs SPATIAL
// block-role partitioning (r6), not temporal in-block phases. Fill is TCC-
// transaction-bound (~28G trans/s, ~272MB, 225-300us in every arrangement)
// -> at floor; r6's fused1 (fill blocks ∥ gemm blocks) restored.
// This round: pullgemm2 M-tile 64->32 (grid 3125 exact, 14KB LDS -> full
// 32-wave/CU occupancy) + 2 rows concurrently per wave (8 gather streams).

constexpr int NN = 100000, RR = 4, EE = 800000;
constexpr int RN = RR * NN;
constexpr int CAP = 32;
constexpr int NG1 = (NN + 63) / 64;     // 1563 gemm1 tiles (M=64)
constexpr int NF  = RR * EE / 512;      // 6250 fill blocks (exact)

typedef short bf16x8 __attribute__((ext_vector_type(8)));
typedef float f32x4 __attribute__((ext_vector_type(4)));

__device__ inline unsigned short f2bf(float f) {
  unsigned u = __float_as_uint(f);
  u += 0x7FFF + ((u >> 16) & 1);
  return (unsigned short)(u >> 16);
}
__device__ inline float bf2f(unsigned short s) {
  return __uint_as_float(((unsigned)s) << 16);
}

// ---- weights -> bf16 [n][k]: BT1 [320][256], BT2 [80][64] ----
__global__ __launch_bounds__(256) void prep_w_kernel(const float* __restrict__ W1,
                                                     const float* __restrict__ L1w,
                                                     const float* __restrict__ W2,
                                                     const float* __restrict__ L2w,
                                                     unsigned short* __restrict__ BT1,
                                                     unsigned short* __restrict__ BT2) {
  int idx = blockIdx.x * 256 + threadIdx.x;
  if (idx < 320 * 256) {
    int n = idx >> 8, k = idx & 255;
    float v = (n < 256) ? W1[((size_t)((n >> 6) * 256 + k)) * 64 + (n & 63)]
                        : L1w[(size_t)k * 64 + (n - 256)];
    BT1[idx] = f2bf(v);
  } else {
    int j = idx - 320 * 256;
    if (j < 80 * 64) {
      int n = j >> 6, k = j & 63;
      float v = (n < 64) ? W2[((size_t)((n >> 4) * 64 + k)) * 16 + (n & 15)]
                         : L2w[(size_t)k * 16 + (n - 64)];
      BT2[j] = f2bf(v);
    }
  }
}

// ---- fused1 (r6 structure): fill blocks ∥ gemm blocks ----
__global__ __launch_bounds__(512) void fused1_kernel(const float* __restrict__ x,
                                                     const unsigned short* __restrict__ BT1,
                                                     const float* __restrict__ L1b,
                                                     const int* __restrict__ src,
                                                     const int* __restrict__ dst,
                                                     int* __restrict__ cursor,
                                                     int* __restrict__ csr_pad,
                                                     unsigned short* __restrict__ hwcat,
                                                     float* __restrict__ h) {
  __shared__ char Al[64 * 64 * 2];    // 8 KB
  __shared__ char Bl[320 * 64 * 2];   // 40 KB
  const int bid = blockIdx.x;
  const bool is_gemm = (bid % 5 == 0) && (bid / 5 < NG1);

  if (!is_gemm) {
    int cnt = (bid + 4) / 5;
    if (cnt > NG1) cnt = NG1;
    int fid = bid - cnt;
    int fl = fid * 512 + threadIdx.x;   // 0..RR*EE-1 (exact)
    int r = fl / EE;
    int idx = dst[fl] * RR + r;         // [v][r] layout
    int pos = atomicAdd(&cursor[idx], 1);
    if (pos < CAP) csr_pad[(size_t)idx * CAP + pos] = src[fl];
    return;
  }

  const int t = threadIdx.x;
  const int m0 = (bid / 5) * 64;
  const int wid = t >> 6, lane = t & 63;
  const int wm = wid >> 2, wn = wid & 3;   // 2 x 4 wave grid
  const int l15 = lane & 15, g = lane >> 4;

  f32x4 acc[2][5];
#pragma unroll
  for (int i = 0; i < 2; ++i)
#pragma unroll
    for (int j = 0; j < 5; ++j) acc[i][j] = (f32x4){0.f, 0.f, 0.f, 0.f};

  for (int kc = 0; kc < 4; ++kc) {
    if (kc) __syncthreads();
#pragma unroll
    for (int it = 0; it < 2; ++it) {
      int fl = t + 512 * it;
      int row = fl >> 4, kq = (fl & 15) * 4;
      int rg = m0 + row;
      float4 v = (rg < NN) ? *(const float4*)(x + (size_t)rg * 256 + kc * 64 + kq)
                           : make_float4(0.f, 0.f, 0.f, 0.f);
      ushort4 pck = {f2bf(v.x), f2bf(v.y), f2bf(v.z), f2bf(v.w)};
      int wb = ((row * 64 + kq) * 2) ^ ((row & 7) << 4);
      *(ushort4*)(Al + wb) = pck;
    }
#pragma unroll
    for (int it = 0; it < 5; ++it) {
      int fl = t + 512 * it;
      int n = fl >> 3, i8 = (fl & 7) * 8;
      uint4 u = *(const uint4*)(BT1 + (size_t)n * 256 + kc * 64 + i8);
      int wb = ((n * 64 + i8) * 2) ^ ((n & 7) << 4);
      *(uint4*)(Bl + wb) = u;
    }
    __syncthreads();
#pragma unroll
    for (int ks = 0; ks < 2; ++ks) {
      bf16x8 af[2], bfr[5];
#pragma unroll
      for (int mi = 0; mi < 2; ++mi) {
        int row = wm * 32 + mi * 16 + l15;
        int byte = ((row * 64 + ks * 32 + g * 8) * 2) ^ ((row & 7) << 4);
        af[mi] = *(const bf16x8*)(Al + byte);
      }
#pragma unroll
      for (int ni = 0; ni < 5; ++ni) {
        int n = wn * 80 + ni * 16 + l15;
        int byte = ((n * 64 + ks * 32 + g * 8) * 2) ^ ((n & 7) << 4);
        bfr[ni] = *(const bf16x8*)(Bl + byte);
      }
#pragma unroll
      for (int mi = 0; mi < 2; ++mi)
#pragma unroll
        for (int ni = 0; ni < 5; ++ni)
          acc[mi][ni] = __builtin_amdgcn_mfma_f32_16x16x32_bf16(af[mi], bfr[ni], acc[mi][ni], 0, 0, 0);
    }
  }
#pragma unroll
  for (int mi = 0; mi < 2; ++mi) {
    int rbase = m0 + wm * 32 + mi * 16 + 4 * g;
#pragma unroll
    for (int ni = 0; ni < 5; ++ni) {
      int n0 = wn * 80 + ni * 16;
      int n = n0 + l15;
#pragma unroll
      for (int e = 0; e < 4; ++e) {
        int row = rbase + e;
        if (row >= NN) continue;
        float v = acc[mi][ni][e];
        if (n0 < 256) hwcat[(size_t)row * 256 + n] = f2bf(v);
        else h[(size_t)row * 64 + (n - 256)] = v + L1b[n - 256];
      }
    }
  }
}

// ---- pullgemm2: M-tile 32, 256 threads, 2 rows concurrent per wave ----
__global__ __launch_bounds__(256) void pullgemm2_kernel(const float* __restrict__ h,
                                                        const unsigned short* __restrict__ hwcat,
                                                        const int* __restrict__ csr_pad,
                                                        const int* __restrict__ cursor,
                                                        const unsigned short* __restrict__ BT2,
                                                        const float* __restrict__ L2b,
                                                        unsigned short* __restrict__ hw2,
                                                        float* __restrict__ out) {
  __shared__ char Al[32 * 64 * 2];   // 4 KB
  __shared__ char Bl[80 * 64 * 2];   // 10 KB
  const int t = threadIdx.x;
  const int m0 = blockIdx.x * 32;    // grid 3125, exact
  const int wid = t >> 6, lane = t & 63;
  const int l15 = lane & 15, g = lane >> 4;

  // phase 1: wave pulls rows wid*8..wid*8+7, two rows concurrently
  for (int ip = 0; ip < 4; ++ip) {
    int row0 = wid * 8 + ip * 2;
    int v0 = m0 + row0, v1 = v0 + 1;
    bool g0 = v0 < NN, g1 = v1 < NN;
    float hv0 = 0.f, hv1 = 0.f;
    int dA[4] = {0, 0, 0, 0}, dB[4] = {0, 0, 0, 0};
    if (g0) { int4 q = *(const int4*)(cursor + v0 * 4); dA[0]=q.x; dA[1]=q.y; dA[2]=q.z; dA[3]=q.w; hv0 = h[(size_t)v0 * 64 + lane]; }
    if (g1) { int4 q = *(const int4*)(cursor + v1 * 4); dB[0]=q.x; dB[1]=q.y; dB[2]=q.z; dB[3]=q.w; hv1 = h[(size_t)v1 * 64 + lane]; }
    const int* lA = csr_pad + (g0 ? (size_t)v0 * (RR * CAP) : 0);
    const int* lB = csr_pad + (g1 ? (size_t)v1 * (RR * CAP) : 0);
    int ddA[4], ddB[4];
    float wA[4], wB[4];
    int dmax = 0;
#pragma unroll
    for (int k = 0; k < 4; ++k) {
      ddA[k] = dA[k] < CAP ? dA[k] : CAP;
      ddB[k] = dB[k] < CAP ? dB[k] : CAP;
      wA[k] = 1.0f / (float)(dA[k] > 1 ? dA[k] : 1);
      wB[k] = 1.0f / (float)(dB[k] > 1 ? dB[k] : 1);
      dmax = dmax > ddA[k] ? dmax : ddA[k];
      dmax = dmax > ddB[k] ? dmax : ddB[k];
    }
    float aA[4] = {0.f, 0.f, 0.f, 0.f}, aB[4] = {0.f, 0.f, 0.f, 0.f};
#pragma unroll 4
    for (int j = 0; j < dmax; ++j) {
#pragma unroll
      for (int k = 0; k < 4; ++k) {
        int eA = lA[k * CAP + j];
        int eB = lB[k * CAP + j];
        int sA = (j < ddA[k]) ? eA : 0;
        int sB = (j < ddB[k]) ? eB : 0;
        float fA = bf2f(hwcat[(size_t)sA * 256 + k * 64 + lane]);
        float fB = bf2f(hwcat[(size_t)sB * 256 + k * 64 + lane]);
        aA[k] += (j < ddA[k]) ? fA : 0.f;
        aB[k] += (j < ddB[k]) ? fB : 0.f;
      }
    }
#pragma unroll
    for (int k = 0; k < 4; ++k) { hv0 += aA[k] * wA[k]; hv1 += aB[k] * wB[k]; }
    hv0 = fmaxf(hv0, 0.f);
    hv1 = fmaxf(hv1, 0.f);
    int wb0 = ((row0 * 64 + lane) * 2) ^ ((row0 & 7) << 4);
    int wb1 = (((row0 + 1) * 64 + lane) * 2) ^ (((row0 + 1) & 7) << 4);
    *(unsigned short*)(Al + wb0) = f2bf(hv0);
    *(unsigned short*)(Al + wb1) = f2bf(hv1);
  }
  // stage B: 80 x 64 bf16 = 640 uint4
#pragma unroll
  for (int it = 0; it < 3; ++it) {
    int fl = t + 256 * it;
    if (fl < 640) {
      int n = fl >> 3, i8 = (fl & 7) * 8;
      uint4 u = *(const uint4*)(BT2 + (size_t)n * 64 + i8);
      int wb = ((n * 64 + i8) * 2) ^ ((n & 7) << 4);
      *(uint4*)(Bl + wb) = u;
    }
  }
  __syncthreads();

  // MFMA: strip = wid>>1 (16 rows), N-half = wid&1 (col-groups 0-2 / 3-4)
  const int strip = wid >> 1;
  const int nbase = (wid & 1) ? 3 : 0;
  const int ncnt  = (wid & 1) ? 2 : 3;
  f32x4 acc[3];
  acc[0] = acc[1] = acc[2] = (f32x4){0.f, 0.f, 0.f, 0.f};
#pragma unroll
  for (int ks = 0; ks < 2; ++ks) {
    int row = strip * 16 + l15;
    int byte = ((row * 64 + ks * 32 + g * 8) * 2) ^ ((row & 7) << 4);
    bf16x8 af = *(const bf16x8*)(Al + byte);
#pragma unroll
    for (int c = 0; c < 3; ++c) {
      if (c < ncnt) {
        int n = (nbase + c) * 16 + l15;
        int nb = ((n * 64 + ks * 32 + g * 8) * 2) ^ ((n & 7) << 4);
        bf16x8 bfr = *(const bf16x8*)(Bl + nb);
        acc[c] = __builtin_amdgcn_mfma_f32_16x16x32_bf16(af, bfr, acc[c], 0, 0, 0);
      }
    }
  }
  int rbase = m0 + strip * 16 + 4 * g;
#pragma unroll
  for (int c = 0; c < 3; ++c) {
    if (c >= ncnt) continue;
    int n0 = (nbase + c) * 16;
    int n = n0 + l15;
#pragma unroll
    for (int e = 0; e < 4; ++e) {
      int row = rbase + e;
      if (row >= NN) continue;
      float vv = acc[c][e];
      if (n0 < 64) hw2[(size_t)row * 64 + n] = f2bf(vv);
      else out[(size_t)row * 16 + (n - 64)] = vv + L2b[n - 64];
    }
  }
}

// ---- pull layer2: lane-group = relation; 4 concurrent lists ----
__global__ __launch_bounds__(256) void pull16_kernel(const unsigned short* __restrict__ hw2,
                                                     const int* __restrict__ csr_pad,
                                                     const int* __restrict__ cursor,
                                                     float* __restrict__ out) {
  int v = blockIdx.x * 4 + (threadIdx.x >> 6);
  if (v >= NN) return;
  int lane = threadIdx.x & 63;
  int c = lane & 15, g = lane >> 4;   // g = relation
  int degg = cursor[v * 4 + g];
  int dd = degg < CAP ? degg : CAP;
  float w = 1.0f / (float)(degg > 1 ? degg : 1);
  const int* lst = csr_pad + (size_t)v * (RR * CAP) + g * CAP;
  float a = 0.f;
#pragma unroll 8
  for (int j = 0; j < dd; ++j) {
    int s = lst[j];
    a += bf2f(hw2[(size_t)s * 64 + g * 16 + c]);
  }
  a *= w;
  a += __shfl_xor(a, 16);
  a += __shfl_xor(a, 32);
  if (lane < 16) out[(size_t)v * 16 + lane] += a;
}

extern "C" void kernel_launch(void* const* d_in, const int* in_sizes, int n_in,
                              void* d_out, int out_size, void* d_ws, size_t ws_size,
                              hipStream_t stream) {
  const float* x   = (const float*)d_in[0];
  const int*   src = (const int*)d_in[1];
  const int*   dst = (const int*)d_in[2];
  const float* W1  = (const float*)d_in[3];
  const float* L1w = (const float*)d_in[4];
  const float* L1b = (const float*)d_in[5];
  const float* W2  = (const float*)d_in[6];
  const float* L2w = (const float*)d_in[7];
  const float* L2b = (const float*)d_in[8];
  float* out = (float*)d_out;

  char* p = (char*)d_ws;
  int* csr_pad = (int*)p;                     p += (size_t)RN * CAP * 4;      // 51.2 MB
  int* cursor  = (int*)p;                     p += (size_t)RN * 4;            // 1.6 MB
  unsigned short* hwcat = (unsigned short*)p; p += (size_t)NN * 256 * 2;      // 51.2 MB
  float* h = (float*)p;                       p += (size_t)NN * 64 * 4;       // 25.6 MB
  unsigned short* hw2 = (unsigned short*)p;   p += (size_t)NN * 64 * 2;       // 12.8 MB
  unsigned short* BT1 = (unsigned short*)p;   p += 320 * 256 * 2;
  unsigned short* BT2 = (unsigned short*)p;   p += 80 * 64 * 2;
  if ((size_t)(p - (char*)d_ws) > ws_size) return;  // visible fail (poison stays)

  hipMemsetAsync(cursor, 0, (size_t)RN * 4, stream);
  prep_w_kernel<<<(320 * 256 + 80 * 64 + 255) / 256, 256, 0, stream>>>(W1, L1w, W2, L2w, BT1, BT2);
  fused1_kernel<<<NG1 + NF, 512, 0, stream>>>(x, BT1, L1b, src, dst, cursor, csr_pad, hwcat, h);
  pullgemm2_kernel<<<NN / 32, 256, 0, stream>>>(h, hwcat, csr_pad, cursor, BT2, L2b, hw2, out);
  pull16_kernel<<<(NN + 3) / 4, 256, 0, stream>>>(hw2, csr_pad, cursor, out);
}

// Round 10
// 372.207 us; speedup vs baseline: 1.3369x; 1.0648x over previous
//
#include <hip/hip_runtime.h>

// EntityClassify (R-GCN) — round 10.
// r9 post-mortem: fill at TCC floor (227us, gemm1 hidden under it). Tail =
// pullgemm2 (~95) + pull16 (~25) + overhead. pullgemm2's gather was load-
// ISSUE-limited: 1 instr = 128B (64 lanes share one edge). This round: 8
// lanes per (edge,rel) slot, dwordx4 per lane -> 1 instr = 8 slots = 1KB.
// Per-rel 1/deg folded into fma; 3x shfl_xor reduce per row. h stored bf16.

constexpr int NN = 100000, RR = 4, EE = 800000;
constexpr int RN = RR * NN;
constexpr int CAP = 32;
constexpr int NG1 = (NN + 63) / 64;     // 1563 gemm1 tiles (M=64)
constexpr int NF  = RR * EE / 512;      // 6250 fill blocks (exact)

typedef short bf16x8 __attribute__((ext_vector_type(8)));
typedef float f32x4 __attribute__((ext_vector_type(4)));

__device__ inline unsigned short f2bf(float f) {
  unsigned u = __float_as_uint(f);
  u += 0x7FFF + ((u >> 16) & 1);
  return (unsigned short)(u >> 16);
}
__device__ inline float bf2f(unsigned short s) {
  return __uint_as_float(((unsigned)s) << 16);
}

// ---- weights -> bf16 [n][k]: BT1 [320][256], BT2 [80][64] ----
__global__ __launch_bounds__(256) void prep_w_kernel(const float* __restrict__ W1,
                                                     const float* __restrict__ L1w,
                                                     const float* __restrict__ W2,
                                                     const float* __restrict__ L2w,
                                                     unsigned short* __restrict__ BT1,
                                                     unsigned short* __restrict__ BT2) {
  int idx = blockIdx.x * 256 + threadIdx.x;
  if (idx < 320 * 256) {
    int n = idx >> 8, k = idx & 255;
    float v = (n < 256) ? W1[((size_t)((n >> 6) * 256 + k)) * 64 + (n & 63)]
                        : L1w[(size_t)k * 64 + (n - 256)];
    BT1[idx] = f2bf(v);
  } else {
    int j = idx - 320 * 256;
    if (j < 80 * 64) {
      int n = j >> 6, k = j & 63;
      float v = (n < 64) ? W2[((size_t)((n >> 4) * 64 + k)) * 16 + (n & 15)]
                         : L2w[(size_t)k * 16 + (n - 64)];
      BT2[j] = f2bf(v);
    }
  }
}

// ---- fused1 (r6 structure): fill blocks ∥ gemm blocks; h stored bf16 ----
__global__ __launch_bounds__(512) void fused1_kernel(const float* __restrict__ x,
                                                     const unsigned short* __restrict__ BT1,
                                                     const float* __restrict__ L1b,
                                                     const int* __restrict__ src,
                                                     const int* __restrict__ dst,
                                                     int* __restrict__ cursor,
                                                     int* __restrict__ csr_pad,
                                                     unsigned short* __restrict__ hwcat,
                                                     unsigned short* __restrict__ h) {
  __shared__ char Al[64 * 64 * 2];    // 8 KB
  __shared__ char Bl[320 * 64 * 2];   // 40 KB
  const int bid = blockIdx.x;
  const bool is_gemm = (bid % 5 == 0) && (bid / 5 < NG1);

  if (!is_gemm) {
    int cnt = (bid + 4) / 5;
    if (cnt > NG1) cnt = NG1;
    int fid = bid - cnt;
    int fl = fid * 512 + threadIdx.x;   // 0..RR*EE-1 (exact)
    int r = fl / EE;
    int idx = dst[fl] * RR + r;         // [v][r] layout
    int pos = atomicAdd(&cursor[idx], 1);
    if (pos < CAP) csr_pad[(size_t)idx * CAP + pos] = src[fl];
    return;
  }

  const int t = threadIdx.x;
  const int m0 = (bid / 5) * 64;
  const int wid = t >> 6, lane = t & 63;
  const int wm = wid >> 2, wn = wid & 3;   // 2 x 4 wave grid
  const int l15 = lane & 15, g = lane >> 4;

  f32x4 acc[2][5];
#pragma unroll
  for (int i = 0; i < 2; ++i)
#pragma unroll
    for (int j = 0; j < 5; ++j) acc[i][j] = (f32x4){0.f, 0.f, 0.f, 0.f};

  for (int kc = 0; kc < 4; ++kc) {
    if (kc) __syncthreads();
#pragma unroll
    for (int it = 0; it < 2; ++it) {
      int fl = t + 512 * it;
      int row = fl >> 4, kq = (fl & 15) * 4;
      int rg = m0 + row;
      float4 v = (rg < NN) ? *(const float4*)(x + (size_t)rg * 256 + kc * 64 + kq)
                           : make_float4(0.f, 0.f, 0.f, 0.f);
      ushort4 pck = {f2bf(v.x), f2bf(v.y), f2bf(v.z), f2bf(v.w)};
      int wb = ((row * 64 + kq) * 2) ^ ((row & 7) << 4);
      *(ushort4*)(Al + wb) = pck;
    }
#pragma unroll
    for (int it = 0; it < 5; ++it) {
      int fl = t + 512 * it;
      int n = fl >> 3, i8 = (fl & 7) * 8;
      uint4 u = *(const uint4*)(BT1 + (size_t)n * 256 + kc * 64 + i8);
      int wb = ((n * 64 + i8) * 2) ^ ((n & 7) << 4);
      *(uint4*)(Bl + wb) = u;
    }
    __syncthreads();
#pragma unroll
    for (int ks = 0; ks < 2; ++ks) {
      bf16x8 af[2], bfr[5];
#pragma unroll
      for (int mi = 0; mi < 2; ++mi) {
        int row = wm * 32 + mi * 16 + l15;
        int byte = ((row * 64 + ks * 32 + g * 8) * 2) ^ ((row & 7) << 4);
        af[mi] = *(const bf16x8*)(Al + byte);
      }
#pragma unroll
      for (int ni = 0; ni < 5; ++ni) {
        int n = wn * 80 + ni * 16 + l15;
        int byte = ((n * 64 + ks * 32 + g * 8) * 2) ^ ((n & 7) << 4);
        bfr[ni] = *(const bf16x8*)(Bl + byte);
      }
#pragma unroll
      for (int mi = 0; mi < 2; ++mi)
#pragma unroll
        for (int ni = 0; ni < 5; ++ni)
          acc[mi][ni] = __builtin_amdgcn_mfma_f32_16x16x32_bf16(af[mi], bfr[ni], acc[mi][ni], 0, 0, 0);
    }
  }
#pragma unroll
  for (int mi = 0; mi < 2; ++mi) {
    int rbase = m0 + wm * 32 + mi * 16 + 4 * g;
#pragma unroll
    for (int ni = 0; ni < 5; ++ni) {
      int n0 = wn * 80 + ni * 16;
      int n = n0 + l15;
#pragma unroll
      for (int e = 0; e < 4; ++e) {
        int row = rbase + e;
        if (row >= NN) continue;
        float v = acc[mi][ni][e];
        if (n0 < 256) hwcat[(size_t)row * 256 + n] = f2bf(v);
        else h[(size_t)row * 64 + (n - 256)] = f2bf(v + L1b[n - 256]);
      }
    }
  }
}

// ---- pullgemm2: M=32 tile; gather = 8 lanes per (edge,rel) slot, 16B/lane ----
__global__ __launch_bounds__(256) void pullgemm2_kernel(const unsigned short* __restrict__ h,
                                                        const unsigned short* __restrict__ hwcat,
                                                        const int* __restrict__ csr_pad,
                                                        const int* __restrict__ cursor,
                                                        const unsigned short* __restrict__ BT2,
                                                        const float* __restrict__ L2b,
                                                        unsigned short* __restrict__ hw2,
                                                        float* __restrict__ out) {
  __shared__ char Al[32 * 64 * 2];   // 4 KB
  __shared__ char Bl[80 * 64 * 2];   // 10 KB
  const int t = threadIdx.x;
  const int m0 = blockIdx.x * 32;    // grid 3125, exact (NN%32==0)
  const int wid = t >> 6, lane = t & 63;
  const int l15 = lane & 15, g = lane >> 4;
  const int slot = lane >> 3;        // 0..7: edge-slot group
  const int cpart = lane & 7;        // 0..7: 8-channel chunk

  // phase 1: wave wid pulls rows wid*8 .. wid*8+7
  for (int i = 0; i < 8; ++i) {
    int row = wid * 8 + i;
    int v = m0 + row;
    int4 dg = *(const int4*)(cursor + v * 4);
    const int* lst = csr_pad + (size_t)v * (RR * CAP);
    float acc[8] = {0.f, 0.f, 0.f, 0.f, 0.f, 0.f, 0.f, 0.f};
#pragma unroll
    for (int k = 0; k < 4; ++k) {
      int d = (&dg.x)[k];
      int dd = d < CAP ? d : CAP;
      float w = 1.0f / (float)(d > 1 ? d : 1);
      for (int p = 0; p < dd; p += 8) {
        int j = p + slot;
        bool pr = j < dd;
        int jr = pr ? j : 0;
        int e = lst[k * CAP + jr];
        int s = pr ? e : 0;                       // bounded before use
        uint4 u = *(const uint4*)(hwcat + (size_t)s * 256 + k * 64 + cpart * 8);
        float wp = pr ? w : 0.f;
#pragma unroll
        for (int q = 0; q < 4; ++q) {
          unsigned uu = (&u.x)[q];
          acc[q * 2]     = fmaf(wp, bf2f((unsigned short)(uu & 0xffffu)), acc[q * 2]);
          acc[q * 2 + 1] = fmaf(wp, bf2f((unsigned short)(uu >> 16)), acc[q * 2 + 1]);
        }
      }
    }
    // reduce across the 8 slot-groups
#pragma unroll
    for (int m = 8; m <= 32; m <<= 1)
#pragma unroll
      for (int q = 0; q < 8; ++q) acc[q] += __shfl_xor(acc[q], m);
    if (slot == 0) {  // lanes 0..7 finalize + write LDS (16B each)
      uint4 hu = *(const uint4*)(h + (size_t)v * 64 + cpart * 8);
      unsigned ow[4];
#pragma unroll
      for (int q = 0; q < 4; ++q) {
        unsigned uu = (&hu.x)[q];
        float v0 = acc[q * 2]     + bf2f((unsigned short)(uu & 0xffffu));
        float v1 = acc[q * 2 + 1] + bf2f((unsigned short)(uu >> 16));
        ow[q] = (unsigned)f2bf(fmaxf(v0, 0.f)) | ((unsigned)f2bf(fmaxf(v1, 0.f)) << 16);
      }
      int eb = ((row * 64 + cpart * 8) * 2) ^ ((row & 7) << 4);
      *(uint4*)(Al + eb) = make_uint4(ow[0], ow[1], ow[2], ow[3]);
    }
  }
  // stage B: 80 x 64 bf16 = 640 uint4
#pragma unroll
  for (int it = 0; it < 3; ++it) {
    int fl = t + 256 * it;
    if (fl < 640) {
      int n = fl >> 3, i8 = (fl & 7) * 8;
      uint4 u = *(const uint4*)(BT2 + (size_t)n * 64 + i8);
      int wb = ((n * 64 + i8) * 2) ^ ((n & 7) << 4);
      *(uint4*)(Bl + wb) = u;
    }
  }
  __syncthreads();

  // MFMA: strip = wid>>1 (16 rows), N-half = wid&1 (col-groups 0-2 / 3-4)
  const int strip = wid >> 1;
  const int nbase = (wid & 1) ? 3 : 0;
  const int ncnt  = (wid & 1) ? 2 : 3;
  f32x4 acc2[3];
  acc2[0] = acc2[1] = acc2[2] = (f32x4){0.f, 0.f, 0.f, 0.f};
#pragma unroll
  for (int ks = 0; ks < 2; ++ks) {
    int row = strip * 16 + l15;
    int byte = ((row * 64 + ks * 32 + g * 8) * 2) ^ ((row & 7) << 4);
    bf16x8 af = *(const bf16x8*)(Al + byte);
#pragma unroll
    for (int c = 0; c < 3; ++c) {
      if (c < ncnt) {
        int n = (nbase + c) * 16 + l15;
        int nb = ((n * 64 + ks * 32 + g * 8) * 2) ^ ((n & 7) << 4);
        bf16x8 bfr = *(const bf16x8*)(Bl + nb);
        acc2[c] = __builtin_amdgcn_mfma_f32_16x16x32_bf16(af, bfr, acc2[c], 0, 0, 0);
      }
    }
  }
  int rbase = m0 + strip * 16 + 4 * g;
#pragma unroll
  for (int c = 0; c < 3; ++c) {
    if (c >= ncnt) continue;
    int n0 = (nbase + c) * 16;
    int n = n0 + l15;
#pragma unroll
    for (int e = 0; e < 4; ++e) {
      int row = rbase + e;
      float vv = acc2[c][e];
      if (n0 < 64) hw2[(size_t)row * 64 + n] = f2bf(vv);
      else out[(size_t)row * 16 + (n - 64)] = vv + L2b[n - 64];
    }
  }
}

// ---- pull layer2: lane-group = relation; 4 concurrent lists ----
__global__ __launch_bounds__(256) void pull16_kernel(const unsigned short* __restrict__ hw2,
                                                     const int* __restrict__ csr_pad,
                                                     const int* __restrict__ cursor,
                                                     float* __restrict__ out) {
  int v = blockIdx.x * 4 + (threadIdx.x >> 6);
  if (v >= NN) return;
  int lane = threadIdx.x & 63;
  int c = lane & 15, g = lane >> 4;   // g = relation
  int degg = cursor[v * 4 + g];
  int dd = degg < CAP ? degg : CAP;
  float w = 1.0f / (float)(degg > 1 ? degg : 1);
  const int* lst = csr_pad + (size_t)v * (RR * CAP) + g * CAP;
  float a = 0.f;
#pragma unroll 8
  for (int j = 0; j < dd; ++j) {
    int s = lst[j];
    a += bf2f(hw2[(size_t)s * 64 + g * 16 + c]);
  }
  a *= w;
  a += __shfl_xor(a, 16);
  a += __shfl_xor(a, 32);
  if (lane < 16) out[(size_t)v * 16 + lane] += a;
}

extern "C" void kernel_launch(void* const* d_in, const int* in_sizes, int n_in,
                              void* d_out, int out_size, void* d_ws, size_t ws_size,
                              hipStream_t stream) {
  const float* x   = (const float*)d_in[0];
  const int*   src = (const int*)d_in[1];
  const int*   dst = (const int*)d_in[2];
  const float* W1  = (const float*)d_in[3];
  const float* L1w = (const float*)d_in[4];
  const float* L1b = (const float*)d_in[5];
  const float* W2  = (const float*)d_in[6];
  const float* L2w = (const float*)d_in[7];
  const float* L2b = (const float*)d_in[8];
  float* out = (float*)d_out;

  char* p = (char*)d_ws;
  int* csr_pad = (int*)p;                     p += (size_t)RN * CAP * 4;      // 51.2 MB
  int* cursor  = (int*)p;                     p += (size_t)RN * 4;            // 1.6 MB
  unsigned short* hwcat = (unsigned short*)p; p += (size_t)NN * 256 * 2;      // 51.2 MB
  unsigned short* h = (unsigned short*)p;     p += (size_t)NN * 64 * 2;       // 12.8 MB
  unsigned short* hw2 = (unsigned short*)p;   p += (size_t)NN * 64 * 2;       // 12.8 MB
  unsigned short* BT1 = (unsigned short*)p;   p += 320 * 256 * 2;
  unsigned short* BT2 = (unsigned short*)p;   p += 80 * 64 * 2;
  if ((size_t)(p - (char*)d_ws) > ws_size) return;  // visible fail (poison stays)

  hipMemsetAsync(cursor, 0, (size_t)RN * 4, stream);
  prep_w_kernel<<<(320 * 256 + 80 * 64 + 255) / 256, 256, 0, stream>>>(W1, L1w, W2, L2w, BT1, BT2);
  fused1_kernel<<<NG1 + NF, 512, 0, stream>>>(x, BT1, L1b, src, dst, cursor, csr_pad, hwcat, h);
  pullgemm2_kernel<<<NN / 32, 256, 0, stream>>>(h, hwcat, csr_pad, cursor, BT2, L2b, hw2, out);
  pull16_kernel<<<(NN + 3) / 4, 256, 0, stream>>>(hw2, csr_pad, cursor, out);
}

// Round 11
// 288.657 us; speedup vs baseline: 1.7238x; 1.2894x over previous
//
#include <hip/hip_runtime.h>

// EntityClassify (R-GCN) — round 11: binned CSR, no memory-side atomics.
// r10 post-mortem: fill's 223us = 3.2M device atomics + 3.2M isolated 32B
// sector writes (51MB target thrashes L2; WRITE_SIZE 260MB -> all to HBM).
// Replace: (1) bin edges into 1563 dst-buckets (64 nodes) via LDS histogram
// + per-(block,bucket) range reservation (306k atomics, L2-mergeable writes);
// (2) pull-L1 builds EXACT per-(node,rel) CSR in LDS per bucket, gathers
// hwcat (r10 8-slot scheme), fuses self+relu+gemm2 MFMA in-block;
// (3) pull-L2 rebuilds LDS CSR, gathers hw2, accumulates out.

constexpr int NN = 100000, RR = 4, EE = 800000;
constexpr int RE = RR * EE;
constexpr int NBKT = (NN + 63) / 64;      // 1563 buckets of 64 dst nodes
constexpr int BCAP = 3072;                // per-bucket edge capacity (λ≈2046)
constexpr int NG1 = (NN + 63) / 64;       // 1563 gemm1 tiles (M=64)
constexpr int CHUNK = 16384;
constexpr int NB = (RE + CHUNK - 1) / CHUNK;  // 196 bin blocks

typedef short bf16x8 __attribute__((ext_vector_type(8)));
typedef float f32x4 __attribute__((ext_vector_type(4)));

__device__ inline unsigned short f2bf(float f) {
  unsigned u = __float_as_uint(f);
  u += 0x7FFF + ((u >> 16) & 1);
  return (unsigned short)(u >> 16);
}
__device__ inline float bf2f(unsigned short s) {
  return __uint_as_float(((unsigned)s) << 16);
}

// ---- weights -> bf16 [n][k]: BT1 [320][256], BT2 [80][64] ----
__global__ __launch_bounds__(256) void prep_w_kernel(const float* __restrict__ W1,
                                                     const float* __restrict__ L1w,
                                                     const float* __restrict__ W2,
                                                     const float* __restrict__ L2w,
                                                     unsigned short* __restrict__ BT1,
                                                     unsigned short* __restrict__ BT2) {
  int idx = blockIdx.x * 256 + threadIdx.x;
  if (idx < 320 * 256) {
    int n = idx >> 8, k = idx & 255;
    float v = (n < 256) ? W1[((size_t)((n >> 6) * 256 + k)) * 64 + (n & 63)]
                        : L1w[(size_t)k * 64 + (n - 256)];
    BT1[idx] = f2bf(v);
  } else {
    int j = idx - 320 * 256;
    if (j < 80 * 64) {
      int n = j >> 6, k = j & 63;
      float v = (n < 64) ? W2[((size_t)((n >> 4) * 64 + k)) * 16 + (n & 15)]
                         : L2w[(size_t)k * 16 + (n - 64)];
      BT2[j] = f2bf(v);
    }
  }
}

// ---- fused1: bin blocks ∥ gemm1 blocks ----
__global__ __launch_bounds__(512) void fused1_kernel(const float* __restrict__ x,
                                                     const unsigned short* __restrict__ BT1,
                                                     const float* __restrict__ L1b,
                                                     const int* __restrict__ src,
                                                     const int* __restrict__ dst,
                                                     int* __restrict__ gcur,
                                                     int* __restrict__ binned,
                                                     unsigned short* __restrict__ hwcat,
                                                     unsigned short* __restrict__ h) {
  __shared__ char lds[49152];
  const int bid = blockIdx.x;
  const int t = threadIdx.x;
  const bool is_bin = (bid % 9 == 0) && (bid / 9 < NB);

  if (is_bin) {
    int* hist = (int*)lds;          // [NBKT]
    int* base = hist + NBKT;        // [NBKT]
    for (int k = t; k < NBKT; k += 512) hist[k] = 0;
    __syncthreads();
    const int e0 = (bid / 9) * CHUNK;
#pragma unroll
    for (int i = 0; i < CHUNK / 512; ++i) {
      int fl = e0 + i * 512 + t;
      if (fl < RE) atomicAdd(&hist[dst[fl] >> 6], 1);
    }
    __syncthreads();
    for (int k = t; k < NBKT; k += 512) {
      int hv = hist[k];
      base[k] = hv ? atomicAdd(&gcur[k], hv) : 0;
      hist[k] = 0;
    }
    __syncthreads();
#pragma unroll
    for (int i = 0; i < CHUNK / 512; ++i) {
      int fl = e0 + i * 512 + t;
      if (fl >= RE) continue;
      int d = dst[fl];
      int b = d >> 6;
      int off = atomicAdd(&hist[b], 1);
      int p = base[b] + off;
      if (p < BCAP) {
        int r = fl / EE;
        binned[(size_t)b * BCAP + p] = src[fl] | (r << 17) | ((d & 63) << 19);
      }
    }
    return;
  }

  // ---- gemm1 role: M-tile 64, N=320, K=256 ----
  int nbins = (bid + 8) / 9;           // bin blocks with id < bid
  if (nbins > NB) nbins = NB;
  const int m0 = (bid - nbins) * 64;
  char* Al = lds;                      // 8 KB
  char* Bl = lds + 64 * 64 * 2;        // 40 KB
  const int wid = t >> 6, lane = t & 63;
  const int wm = wid >> 2, wn = wid & 3;
  const int l15 = lane & 15, g = lane >> 4;

  f32x4 acc[2][5];
#pragma unroll
  for (int i = 0; i < 2; ++i)
#pragma unroll
    for (int j = 0; j < 5; ++j) acc[i][j] = (f32x4){0.f, 0.f, 0.f, 0.f};

  for (int kc = 0; kc < 4; ++kc) {
    if (kc) __syncthreads();
#pragma unroll
    for (int it = 0; it < 2; ++it) {
      int fl = t + 512 * it;
      int row = fl >> 4, kq = (fl & 15) * 4;
      int rg = m0 + row;
      float4 v = (rg < NN) ? *(const float4*)(x + (size_t)rg * 256 + kc * 64 + kq)
                           : make_float4(0.f, 0.f, 0.f, 0.f);
      ushort4 pck = {f2bf(v.x), f2bf(v.y), f2bf(v.z), f2bf(v.w)};
      int wb = ((row * 64 + kq) * 2) ^ ((row & 7) << 4);
      *(ushort4*)(Al + wb) = pck;
    }
#pragma unroll
    for (int it = 0; it < 5; ++it) {
      int fl = t + 512 * it;
      int n = fl >> 3, i8 = (fl & 7) * 8;
      uint4 u = *(const uint4*)(BT1 + (size_t)n * 256 + kc * 64 + i8);
      int wb = ((n * 64 + i8) * 2) ^ ((n & 7) << 4);
      *(uint4*)(Bl + wb) = u;
    }
    __syncthreads();
#pragma unroll
    for (int ks = 0; ks < 2; ++ks) {
      bf16x8 af[2], bfr[5];
#pragma unroll
      for (int mi = 0; mi < 2; ++mi) {
        int row = wm * 32 + mi * 16 + l15;
        int byte = ((row * 64 + ks * 32 + g * 8) * 2) ^ ((row & 7) << 4);
        af[mi] = *(const bf16x8*)(Al + byte);
      }
#pragma unroll
      for (int ni = 0; ni < 5; ++ni) {
        int n = wn * 80 + ni * 16 + l15;
        int byte = ((n * 64 + ks * 32 + g * 8) * 2) ^ ((n & 7) << 4);
        bfr[ni] = *(const bf16x8*)(Bl + byte);
      }
#pragma unroll
      for (int mi = 0; mi < 2; ++mi)
#pragma unroll
        for (int ni = 0; ni < 5; ++ni)
          acc[mi][ni] = __builtin_amdgcn_mfma_f32_16x16x32_bf16(af[mi], bfr[ni], acc[mi][ni], 0, 0, 0);
    }
  }
#pragma unroll
  for (int mi = 0; mi < 2; ++mi) {
    int rbase = m0 + wm * 32 + mi * 16 + 4 * g;
#pragma unroll
    for (int ni = 0; ni < 5; ++ni) {
      int n0 = wn * 80 + ni * 16;
      int n = n0 + l15;
#pragma unroll
      for (int e = 0; e < 4; ++e) {
        int row = rbase + e;
        if (row >= NN) continue;
        float v = acc[mi][ni][e];
        if (n0 < 256) hwcat[(size_t)row * 256 + n] = f2bf(v);
        else h[(size_t)row * 64 + (n - 256)] = f2bf(v + L1b[n - 256]);
      }
    }
  }
}

// ---- pull-L1 + gemm2: one block per bucket (64 nodes) ----
__global__ __launch_bounds__(256) void pull1_kernel(const unsigned short* __restrict__ h,
                                                    const unsigned short* __restrict__ hwcat,
                                                    const int* __restrict__ binned,
                                                    const int* __restrict__ gcur,
                                                    const unsigned short* __restrict__ BT2,
                                                    const float* __restrict__ L2b,
                                                    unsigned short* __restrict__ hw2,
                                                    float* __restrict__ out) {
  __shared__ int csr[BCAP];            // 12 KB; later overlaid by B2 stage
  __shared__ int cnt[256];
  __shared__ int off[256];
  __shared__ int deg[256];
  __shared__ float htile[64][64];      // 16 KB; later overlaid by A bf16 tile
  const int t = threadIdx.x, bkt = blockIdx.x;
  const int wid = t >> 6, lane = t & 63;
  const int l15 = lane & 15, g = lane >> 4;

  int count = gcur[bkt];
  if (count > BCAP) count = BCAP;
  const int* edges = binned + (size_t)bkt * BCAP;

  // CSR build: count -> scan -> place
  cnt[t] = 0;
  __syncthreads();
  for (int i = t; i < count; i += 256) {
    int w = edges[i];
    atomicAdd(&cnt[((w >> 19) & 63) * 4 + ((w >> 17) & 3)], 1);
  }
  __syncthreads();
  off[t] = cnt[t];
  __syncthreads();
  for (int s = 1; s < 256; s <<= 1) {
    int v = (t >= s) ? off[t - s] : 0;
    __syncthreads();
    off[t] += v;
    __syncthreads();
  }
  int excl = off[t] - cnt[t];
  deg[t] = cnt[t];
  __syncthreads();
  off[t] = excl;
  cnt[t] = excl;                        // becomes placement cursor
  __syncthreads();
  for (int i = t; i < count; i += 256) {
    int w = edges[i];
    int k = ((w >> 19) & 63) * 4 + ((w >> 17) & 3);
    int p = atomicAdd(&cnt[k], 1);
    csr[p] = w & 0x1FFFF;
  }
  __syncthreads();

  // gather: wave wid handles nodes wid*16..+15; 8 lanes per edge-slot, 16B each
  const int slot = lane >> 3, cpart = lane & 7;
  for (int ii = 0; ii < 16; ++ii) {
    int nloc = wid * 16 + ii;
    float acc[8] = {0.f, 0.f, 0.f, 0.f, 0.f, 0.f, 0.f, 0.f};
#pragma unroll
    for (int r = 0; r < 4; ++r) {
      int k = nloc * 4 + r;
      int beg = off[k], dg = deg[k];
      float w = 1.0f / (float)(dg > 1 ? dg : 1);
      for (int p0 = 0; p0 < dg; p0 += 8) {
        int j = p0 + slot;
        bool pr = j < dg;
        int s = pr ? csr[beg + j] : 0;
        uint4 u = *(const uint4*)(hwcat + (size_t)s * 256 + r * 64 + cpart * 8);
        float wp = pr ? w : 0.f;
#pragma unroll
        for (int q = 0; q < 4; ++q) {
          unsigned uu = (&u.x)[q];
          acc[q * 2]     = fmaf(wp, bf2f((unsigned short)(uu & 0xffffu)), acc[q * 2]);
          acc[q * 2 + 1] = fmaf(wp, bf2f((unsigned short)(uu >> 16)), acc[q * 2 + 1]);
        }
      }
    }
#pragma unroll
    for (int m = 8; m <= 32; m <<= 1)
#pragma unroll
      for (int q = 0; q < 8; ++q) acc[q] += __shfl_xor(acc[q], m);
    if (slot == 0) {
      *(float4*)&htile[nloc][cpart * 8]     = make_float4(acc[0], acc[1], acc[2], acc[3]);
      *(float4*)&htile[nloc][cpart * 8 + 4] = make_float4(acc[4], acc[5], acc[6], acc[7]);
    }
  }
  __syncthreads();

  // self + relu -> bf16 regs (read htile f32 before overlay-write)
  const int row = t >> 2, c0 = (t & 3) * 16;
  const int gn = bkt * 64 + row;
  float vals[16];
#pragma unroll
  for (int q = 0; q < 16; ++q) vals[q] = htile[row][c0 + q];
  if (gn < NN) {
    uint4 h0 = *(const uint4*)(h + (size_t)gn * 64 + c0);
    uint4 h1 = *(const uint4*)(h + (size_t)gn * 64 + c0 + 8);
#pragma unroll
    for (int q = 0; q < 4; ++q) {
      unsigned a = (&h0.x)[q], b = (&h1.x)[q];
      vals[q * 2]     += bf2f((unsigned short)(a & 0xffffu));
      vals[q * 2 + 1] += bf2f((unsigned short)(a >> 16));
      vals[8 + q * 2]     += bf2f((unsigned short)(b & 0xffffu));
      vals[8 + q * 2 + 1] += bf2f((unsigned short)(b >> 16));
    }
  }
  unsigned pk[8];
#pragma unroll
  for (int q = 0; q < 8; ++q) {
    float v0 = fmaxf(vals[q * 2], 0.f), v1 = fmaxf(vals[q * 2 + 1], 0.f);
    pk[q] = (unsigned)f2bf(v0) | ((unsigned)f2bf(v1) << 16);
  }
  __syncthreads();

  // overlay: A bf16 tile over htile region; B2 over csr region
  char* Al = (char*)htile;
  {
    int wb = ((row * 64 + c0) * 2) ^ ((row & 7) << 4);
    *(uint4*)(Al + wb) = make_uint4(pk[0], pk[1], pk[2], pk[3]);
    int wb2 = ((row * 64 + c0 + 8) * 2) ^ ((row & 7) << 4);
    *(uint4*)(Al + wb2) = make_uint4(pk[4], pk[5], pk[6], pk[7]);
  }
  char* Bl = (char*)csr;
#pragma unroll
  for (int it = 0; it < 3; ++it) {
    int fl = t + 256 * it;
    if (fl < 640) {
      int n = fl >> 3, i8 = (fl & 7) * 8;
      uint4 u = *(const uint4*)(BT2 + (size_t)n * 64 + i8);
      int wb = ((n * 64 + i8) * 2) ^ ((n & 7) << 4);
      *(uint4*)(Bl + wb) = u;
    }
  }
  __syncthreads();

  // gemm2: wave wid -> rows wid*16..+15, N=80
  f32x4 acc2[5];
#pragma unroll
  for (int j = 0; j < 5; ++j) acc2[j] = (f32x4){0.f, 0.f, 0.f, 0.f};
#pragma unroll
  for (int ks = 0; ks < 2; ++ks) {
    int ra = wid * 16 + l15;
    int byte = ((ra * 64 + ks * 32 + g * 8) * 2) ^ ((ra & 7) << 4);
    bf16x8 af = *(const bf16x8*)(Al + byte);
#pragma unroll
    for (int ni = 0; ni < 5; ++ni) {
      int n = ni * 16 + l15;
      int nb = ((n * 64 + ks * 32 + g * 8) * 2) ^ ((n & 7) << 4);
      bf16x8 bfr = *(const bf16x8*)(Bl + nb);
      acc2[ni] = __builtin_amdgcn_mfma_f32_16x16x32_bf16(af, bfr, acc2[ni], 0, 0, 0);
    }
  }
  int rb = wid * 16 + 4 * g;
#pragma unroll
  for (int ni = 0; ni < 5; ++ni) {
    int n0 = ni * 16;
    int n = n0 + l15;
#pragma unroll
    for (int e = 0; e < 4; ++e) {
      int gno = bkt * 64 + rb + e;
      if (gno >= NN) continue;
      float vv = acc2[ni][e];
      if (n0 < 64) hw2[(size_t)gno * 64 + n] = f2bf(vv);
      else out[(size_t)gno * 16 + (n - 64)] = vv + L2b[n - 64];
    }
  }
}

// ---- pull-L2: rebuild LDS CSR, gather hw2 (16 ch/edge), accumulate out ----
__global__ __launch_bounds__(256) void pull2_kernel(const unsigned short* __restrict__ hw2,
                                                    const int* __restrict__ binned,
                                                    const int* __restrict__ gcur,
                                                    float* __restrict__ out) {
  __shared__ int csr[BCAP];
  __shared__ int cnt[256];
  __shared__ int off[256];
  __shared__ int deg[256];
  __shared__ float ot[64][16];
  const int t = threadIdx.x, bkt = blockIdx.x;
  const int wid = t >> 6, lane = t & 63;

  int count = gcur[bkt];
  if (count > BCAP) count = BCAP;
  const int* edges = binned + (size_t)bkt * BCAP;

  cnt[t] = 0;
  __syncthreads();
  for (int i = t; i < count; i += 256) {
    int w = edges[i];
    atomicAdd(&cnt[((w >> 19) & 63) * 4 + ((w >> 17) & 3)], 1);
  }
  __syncthreads();
  off[t] = cnt[t];
  __syncthreads();
  for (int s = 1; s < 256; s <<= 1) {
    int v = (t >= s) ? off[t - s] : 0;
    __syncthreads();
    off[t] += v;
    __syncthreads();
  }
  int excl = off[t] - cnt[t];
  deg[t] = cnt[t];
  __syncthreads();
  off[t] = excl;
  cnt[t] = excl;
  __syncthreads();
  for (int i = t; i < count; i += 256) {
    int w = edges[i];
    int k = ((w >> 19) & 63) * 4 + ((w >> 17) & 3);
    int p = atomicAdd(&cnt[k], 1);
    csr[p] = w & 0x1FFFF;
  }
  __syncthreads();

  // gather: 4 lanes per edge-slot (16 slots), 8B (4 ch) per lane
  const int slot = lane >> 2, cpart = lane & 3;
  for (int ii = 0; ii < 16; ++ii) {
    int nloc = wid * 16 + ii;
    float acc[4] = {0.f, 0.f, 0.f, 0.f};
#pragma unroll
    for (int r = 0; r < 4; ++r) {
      int k = nloc * 4 + r;
      int beg = off[k], dg = deg[k];
      float w = 1.0f / (float)(dg > 1 ? dg : 1);
      for (int p0 = 0; p0 < dg; p0 += 16) {
        int j = p0 + slot;
        bool pr = j < dg;
        int s = pr ? csr[beg + j] : 0;
        uint2 u = *(const uint2*)(hw2 + (size_t)s * 64 + r * 16 + cpart * 4);
        float wp = pr ? w : 0.f;
        acc[0] = fmaf(wp, bf2f((unsigned short)(u.x & 0xffffu)), acc[0]);
        acc[1] = fmaf(wp, bf2f((unsigned short)(u.x >> 16)), acc[1]);
        acc[2] = fmaf(wp, bf2f((unsigned short)(u.y & 0xffffu)), acc[2]);
        acc[3] = fmaf(wp, bf2f((unsigned short)(u.y >> 16)), acc[3]);
      }
    }
#pragma unroll
    for (int m = 4; m <= 32; m <<= 1)
#pragma unroll
      for (int q = 0; q < 4; ++q) acc[q] += __shfl_xor(acc[q], m);
    if (slot == 0)
      *(float4*)&ot[nloc][cpart * 4] = make_float4(acc[0], acc[1], acc[2], acc[3]);
  }
  __syncthreads();

  // out += ot (coalesced)
  int row = t >> 2, q = t & 3;
  int gn = bkt * 64 + row;
  if (gn < NN) {
    float4 o = *(float4*)(out + (size_t)gn * 16 + q * 4);
    float4 a = *(float4*)&ot[row][q * 4];
    o.x += a.x; o.y += a.y; o.z += a.z; o.w += a.w;
    *(float4*)(out + (size_t)gn * 16 + q * 4) = o;
  }
}

extern "C" void kernel_launch(void* const* d_in, const int* in_sizes, int n_in,
                              void* d_out, int out_size, void* d_ws, size_t ws_size,
                              hipStream_t stream) {
  const float* x   = (const float*)d_in[0];
  const int*   src = (const int*)d_in[1];
  const int*   dst = (const int*)d_in[2];
  const float* W1  = (const float*)d_in[3];
  const float* L1w = (const float*)d_in[4];
  const float* L1b = (const float*)d_in[5];
  const float* W2  = (const float*)d_in[6];
  const float* L2w = (const float*)d_in[7];
  const float* L2b = (const float*)d_in[8];
  float* out = (float*)d_out;

  char* p = (char*)d_ws;
  int* binned = (int*)p;                      p += (size_t)NBKT * BCAP * 4;   // 19.2 MB
  int* gcur   = (int*)p;                      p += 8192;                      // 6.3 KB used
  unsigned short* hwcat = (unsigned short*)p; p += (size_t)NN * 256 * 2;      // 51.2 MB
  unsigned short* h = (unsigned short*)p;     p += (size_t)NN * 64 * 2;       // 12.8 MB
  unsigned short* hw2 = (unsigned short*)p;   p += (size_t)NN * 64 * 2;       // 12.8 MB
  unsigned short* BT1 = (unsigned short*)p;   p += 320 * 256 * 2;
  unsigned short* BT2 = (unsigned short*)p;   p += 80 * 64 * 2;
  if ((size_t)(p - (char*)d_ws) > ws_size) return;  // visible fail (poison stays)

  hipMemsetAsync(gcur, 0, NBKT * 4, stream);
  prep_w_kernel<<<(320 * 256 + 80 * 64 + 255) / 256, 256, 0, stream>>>(W1, L1w, W2, L2w, BT1, BT2);
  fused1_kernel<<<NG1 + NB, 512, 0, stream>>>(x, BT1, L1b, src, dst, gcur, binned, hwcat, h);
  pull1_kernel<<<NBKT, 256, 0, stream>>>(h, hwcat, binned, gcur, BT2, L2b, hw2, out);
  pull2_kernel<<<NBKT, 256, 0, stream>>>(hw2, binned, gcur, out);
}

// Round 12
// 263.631 us; speedup vs baseline: 1.8875x; 1.0949x over previous
//
#include <hip/hip_runtime.h>

// EntityClassify (R-GCN) — round 12.
// r11 post-mortem: 289us; fused1=172us with Occ 24% (= 8 waves/CU = one
// 512-thr block/CU) -> the 196 bin blocks are a straggler tail (gemm done).
// Fix: (a) CHUNK 16384->8192 (391 bin blocks, 2x CU parallelism, half serial
// length); (b) cache dst/src in registers during histogram pass -> scatter
// pass has NO global reloads (kills the dependent reload chain); (c) bins
// interleaved every 5th block. pull1/pull2 unchanged from r11.

constexpr int NN = 100000, RR = 4, EE = 800000;
constexpr int RE = RR * EE;
constexpr int NBKT = (NN + 63) / 64;      // 1563 buckets of 64 dst nodes
constexpr int BCAP = 3072;                // per-bucket capacity (λ≈2046, σ≈45)
constexpr int NG1 = (NN + 63) / 64;       // 1563 gemm1 tiles (M=64)
constexpr int CHUNK = 8192;
constexpr int NB = (RE + CHUNK - 1) / CHUNK;  // 391 bin blocks
constexpr int EPT = CHUNK / 512;          // 16 edges per thread

typedef short bf16x8 __attribute__((ext_vector_type(8)));
typedef float f32x4 __attribute__((ext_vector_type(4)));

__device__ inline unsigned short f2bf(float f) {
  unsigned u = __float_as_uint(f);
  u += 0x7FFF + ((u >> 16) & 1);
  return (unsigned short)(u >> 16);
}
__device__ inline float bf2f(unsigned short s) {
  return __uint_as_float(((unsigned)s) << 16);
}

// ---- weights -> bf16 [n][k]: BT1 [320][256], BT2 [80][64] ----
__global__ __launch_bounds__(256) void prep_w_kernel(const float* __restrict__ W1,
                                                     const float* __restrict__ L1w,
                                                     const float* __restrict__ W2,
                                                     const float* __restrict__ L2w,
                                                     unsigned short* __restrict__ BT1,
                                                     unsigned short* __restrict__ BT2) {
  int idx = blockIdx.x * 256 + threadIdx.x;
  if (idx < 320 * 256) {
    int n = idx >> 8, k = idx & 255;
    float v = (n < 256) ? W1[((size_t)((n >> 6) * 256 + k)) * 64 + (n & 63)]
                        : L1w[(size_t)k * 64 + (n - 256)];
    BT1[idx] = f2bf(v);
  } else {
    int j = idx - 320 * 256;
    if (j < 80 * 64) {
      int n = j >> 6, k = j & 63;
      float v = (n < 64) ? W2[((size_t)((n >> 4) * 64 + k)) * 16 + (n & 15)]
                         : L2w[(size_t)k * 16 + (n - 64)];
      BT2[j] = f2bf(v);
    }
  }
}

// ---- fused1: bin blocks (every 5th) ∥ gemm1 blocks ----
__global__ __launch_bounds__(512) void fused1_kernel(const float* __restrict__ x,
                                                     const unsigned short* __restrict__ BT1,
                                                     const float* __restrict__ L1b,
                                                     const int* __restrict__ src,
                                                     const int* __restrict__ dst,
                                                     int* __restrict__ gcur,
                                                     int* __restrict__ binned,
                                                     unsigned short* __restrict__ hwcat,
                                                     unsigned short* __restrict__ h) {
  __shared__ char lds[49152];
  const int bid = blockIdx.x;
  const int t = threadIdx.x;
  const bool is_bin = (bid % 5 == 0) && (bid / 5 < NB);

  if (is_bin) {
    int* hist = (int*)lds;          // [NBKT]
    int* base = hist + NBKT;        // [NBKT]
    for (int k = t; k < NBKT; k += 512) hist[k] = 0;
    __syncthreads();
    const int e0 = (bid / 5) * CHUNK + t;
    int dl[EPT], sl[EPT];
#pragma unroll
    for (int i = 0; i < EPT; ++i) {
      int fl = e0 + i * 512;
      dl[i] = -1;
      if (fl < RE) {
        dl[i] = dst[fl];
        sl[i] = src[fl];
        atomicAdd(&hist[dl[i] >> 6], 1);
      }
    }
    __syncthreads();
    for (int k = t; k < NBKT; k += 512) {
      int hv = hist[k];
      base[k] = hv ? atomicAdd(&gcur[k], hv) : 0;
      hist[k] = 0;
    }
    __syncthreads();
#pragma unroll
    for (int i = 0; i < EPT; ++i) {
      if (dl[i] < 0) continue;
      int fl = e0 + i * 512;
      int r = fl / EE;
      int b = dl[i] >> 6;
      int off = atomicAdd(&hist[b], 1);
      int p = base[b] + off;
      if (p < BCAP) binned[(size_t)b * BCAP + p] = sl[i] | (r << 17) | ((dl[i] & 63) << 19);
    }
    return;
  }

  // ---- gemm1 role: M-tile 64, N=320, K=256 ----
  int nbins = (bid + 4) / 5;           // bin blocks with id < bid
  if (nbins > NB) nbins = NB;
  const int m0 = (bid - nbins) * 64;
  char* Al = lds;                      // 8 KB
  char* Bl = lds + 64 * 64 * 2;        // 40 KB
  const int wid = t >> 6, lane = t & 63;
  const int wm = wid >> 2, wn = wid & 3;
  const int l15 = lane & 15, g = lane >> 4;

  f32x4 acc[2][5];
#pragma unroll
  for (int i = 0; i < 2; ++i)
#pragma unroll
    for (int j = 0; j < 5; ++j) acc[i][j] = (f32x4){0.f, 0.f, 0.f, 0.f};

  for (int kc = 0; kc < 4; ++kc) {
    if (kc) __syncthreads();
#pragma unroll
    for (int it = 0; it < 2; ++it) {
      int fl = t + 512 * it;
      int row = fl >> 4, kq = (fl & 15) * 4;
      int rg = m0 + row;
      float4 v = (rg < NN) ? *(const float4*)(x + (size_t)rg * 256 + kc * 64 + kq)
                           : make_float4(0.f, 0.f, 0.f, 0.f);
      ushort4 pck = {f2bf(v.x), f2bf(v.y), f2bf(v.z), f2bf(v.w)};
      int wb = ((row * 64 + kq) * 2) ^ ((row & 7) << 4);
      *(ushort4*)(Al + wb) = pck;
    }
#pragma unroll
    for (int it = 0; it < 5; ++it) {
      int fl = t + 512 * it;
      int n = fl >> 3, i8 = (fl & 7) * 8;
      uint4 u = *(const uint4*)(BT1 + (size_t)n * 256 + kc * 64 + i8);
      int wb = ((n * 64 + i8) * 2) ^ ((n & 7) << 4);
      *(uint4*)(Bl + wb) = u;
    }
    __syncthreads();
#pragma unroll
    for (int ks = 0; ks < 2; ++ks) {
      bf16x8 af[2], bfr[5];
#pragma unroll
      for (int mi = 0; mi < 2; ++mi) {
        int row = wm * 32 + mi * 16 + l15;
        int byte = ((row * 64 + ks * 32 + g * 8) * 2) ^ ((row & 7) << 4);
        af[mi] = *(const bf16x8*)(Al + byte);
      }
#pragma unroll
      for (int ni = 0; ni < 5; ++ni) {
        int n = wn * 80 + ni * 16 + l15;
        int byte = ((n * 64 + ks * 32 + g * 8) * 2) ^ ((n & 7) << 4);
        bfr[ni] = *(const bf16x8*)(Bl + byte);
      }
#pragma unroll
      for (int mi = 0; mi < 2; ++mi)
#pragma unroll
        for (int ni = 0; ni < 5; ++ni)
          acc[mi][ni] = __builtin_amdgcn_mfma_f32_16x16x32_bf16(af[mi], bfr[ni], acc[mi][ni], 0, 0, 0);
    }
  }
#pragma unroll
  for (int mi = 0; mi < 2; ++mi) {
    int rbase = m0 + wm * 32 + mi * 16 + 4 * g;
#pragma unroll
    for (int ni = 0; ni < 5; ++ni) {
      int n0 = wn * 80 + ni * 16;
      int n = n0 + l15;
#pragma unroll
      for (int e = 0; e < 4; ++e) {
        int row = rbase + e;
        if (row >= NN) continue;
        float v = acc[mi][ni][e];
        if (n0 < 256) hwcat[(size_t)row * 256 + n] = f2bf(v);
        else h[(size_t)row * 64 + (n - 256)] = f2bf(v + L1b[n - 256]);
      }
    }
  }
}

// ---- pull-L1 + gemm2: one block per bucket (64 nodes) ----
__global__ __launch_bounds__(256) void pull1_kernel(const unsigned short* __restrict__ h,
                                                    const unsigned short* __restrict__ hwcat,
                                                    const int* __restrict__ binned,
                                                    const int* __restrict__ gcur,
                                                    const unsigned short* __restrict__ BT2,
                                                    const float* __restrict__ L2b,
                                                    unsigned short* __restrict__ hw2,
                                                    float* __restrict__ out) {
  __shared__ int csr[BCAP];            // 12 KB; later overlaid by B2 stage
  __shared__ int cnt[256];
  __shared__ int off[256];
  __shared__ int deg[256];
  __shared__ float htile[64][64];      // 16 KB; later overlaid by A bf16 tile
  const int t = threadIdx.x, bkt = blockIdx.x;
  const int wid = t >> 6, lane = t & 63;
  const int l15 = lane & 15, g = lane >> 4;

  int count = gcur[bkt];
  if (count > BCAP) count = BCAP;
  const int* edges = binned + (size_t)bkt * BCAP;

  cnt[t] = 0;
  __syncthreads();
  for (int i = t; i < count; i += 256) {
    int w = edges[i];
    atomicAdd(&cnt[((w >> 19) & 63) * 4 + ((w >> 17) & 3)], 1);
  }
  __syncthreads();
  off[t] = cnt[t];
  __syncthreads();
  for (int s = 1; s < 256; s <<= 1) {
    int v = (t >= s) ? off[t - s] : 0;
    __syncthreads();
    off[t] += v;
    __syncthreads();
  }
  int excl = off[t] - cnt[t];
  deg[t] = cnt[t];
  __syncthreads();
  off[t] = excl;
  cnt[t] = excl;                        // becomes placement cursor
  __syncthreads();
  for (int i = t; i < count; i += 256) {
    int w = edges[i];
    int k = ((w >> 19) & 63) * 4 + ((w >> 17) & 3);
    int p = atomicAdd(&cnt[k], 1);
    csr[p] = w & 0x1FFFF;
  }
  __syncthreads();

  // gather: wave wid handles nodes wid*16..+15; 8 lanes per edge-slot, 16B each
  const int slot = lane >> 3, cpart = lane & 7;
  for (int ii = 0; ii < 16; ++ii) {
    int nloc = wid * 16 + ii;
    float acc[8] = {0.f, 0.f, 0.f, 0.f, 0.f, 0.f, 0.f, 0.f};
#pragma unroll
    for (int r = 0; r < 4; ++r) {
      int k = nloc * 4 + r;
      int beg = off[k], dg = deg[k];
      float w = 1.0f / (float)(dg > 1 ? dg : 1);
      for (int p0 = 0; p0 < dg; p0 += 8) {
        int j = p0 + slot;
        bool pr = j < dg;
        int s = pr ? csr[beg + j] : 0;
        uint4 u = *(const uint4*)(hwcat + (size_t)s * 256 + r * 64 + cpart * 8);
        float wp = pr ? w : 0.f;
#pragma unroll
        for (int q = 0; q < 4; ++q) {
          unsigned uu = (&u.x)[q];
          acc[q * 2]     = fmaf(wp, bf2f((unsigned short)(uu & 0xffffu)), acc[q * 2]);
          acc[q * 2 + 1] = fmaf(wp, bf2f((unsigned short)(uu >> 16)), acc[q * 2 + 1]);
        }
      }
    }
#pragma unroll
    for (int m = 8; m <= 32; m <<= 1)
#pragma unroll
      for (int q = 0; q < 8; ++q) acc[q] += __shfl_xor(acc[q], m);
    if (slot == 0) {
      *(float4*)&htile[nloc][cpart * 8]     = make_float4(acc[0], acc[1], acc[2], acc[3]);
      *(float4*)&htile[nloc][cpart * 8 + 4] = make_float4(acc[4], acc[5], acc[6], acc[7]);
    }
  }
  __syncthreads();

  // self + relu -> bf16 regs (read htile f32 before overlay-write)
  const int row = t >> 2, c0 = (t & 3) * 16;
  const int gn = bkt * 64 + row;
  float vals[16];
#pragma unroll
  for (int q = 0; q < 16; ++q) vals[q] = htile[row][c0 + q];
  if (gn < NN) {
    uint4 h0 = *(const uint4*)(h + (size_t)gn * 64 + c0);
    uint4 h1 = *(const uint4*)(h + (size_t)gn * 64 + c0 + 8);
#pragma unroll
    for (int q = 0; q < 4; ++q) {
      unsigned a = (&h0.x)[q], b = (&h1.x)[q];
      vals[q * 2]     += bf2f((unsigned short)(a & 0xffffu));
      vals[q * 2 + 1] += bf2f((unsigned short)(a >> 16));
      vals[8 + q * 2]     += bf2f((unsigned short)(b & 0xffffu));
      vals[8 + q * 2 + 1] += bf2f((unsigned short)(b >> 16));
    }
  }
  unsigned pk[8];
#pragma unroll
  for (int q = 0; q < 8; ++q) {
    float v0 = fmaxf(vals[q * 2], 0.f), v1 = fmaxf(vals[q * 2 + 1], 0.f);
    pk[q] = (unsigned)f2bf(v0) | ((unsigned)f2bf(v1) << 16);
  }
  __syncthreads();

  // overlay: A bf16 tile over htile region; B2 over csr region
  char* Al = (char*)htile;
  {
    int wb = ((row * 64 + c0) * 2) ^ ((row & 7) << 4);
    *(uint4*)(Al + wb) = make_uint4(pk[0], pk[1], pk[2], pk[3]);
    int wb2 = ((row * 64 + c0 + 8) * 2) ^ ((row & 7) << 4);
    *(uint4*)(Al + wb2) = make_uint4(pk[4], pk[5], pk[6], pk[7]);
  }
  char* Bl = (char*)csr;
#pragma unroll
  for (int it = 0; it < 3; ++it) {
    int fl = t + 256 * it;
    if (fl < 640) {
      int n = fl >> 3, i8 = (fl & 7) * 8;
      uint4 u = *(const uint4*)(BT2 + (size_t)n * 64 + i8);
      int wb = ((n * 64 + i8) * 2) ^ ((n & 7) << 4);
      *(uint4*)(Bl + wb) = u;
    }
  }
  __syncthreads();

  // gemm2: wave wid -> rows wid*16..+15, N=80
  f32x4 acc2[5];
#pragma unroll
  for (int j = 0; j < 5; ++j) acc2[j] = (f32x4){0.f, 0.f, 0.f, 0.f};
#pragma unroll
  for (int ks = 0; ks < 2; ++ks) {
    int ra = wid * 16 + l15;
    int byte = ((ra * 64 + ks * 32 + g * 8) * 2) ^ ((ra & 7) << 4);
    bf16x8 af = *(const bf16x8*)(Al + byte);
#pragma unroll
    for (int ni = 0; ni < 5; ++ni) {
      int n = ni * 16 + l15;
      int nb = ((n * 64 + ks * 32 + g * 8) * 2) ^ ((n & 7) << 4);
      bf16x8 bfr = *(const bf16x8*)(Bl + nb);
      acc2[ni] = __builtin_amdgcn_mfma_f32_16x16x32_bf16(af, bfr, acc2[ni], 0, 0, 0);
    }
  }
  int rb = wid * 16 + 4 * g;
#pragma unroll
  for (int ni = 0; ni < 5; ++ni) {
    int n0 = ni * 16;
    int n = n0 + l15;
#pragma unroll
    for (int e = 0; e < 4; ++e) {
      int gno = bkt * 64 + rb + e;
      if (gno >= NN) continue;
      float vv = acc2[ni][e];
      if (n0 < 64) hw2[(size_t)gno * 64 + n] = f2bf(vv);
      else out[(size_t)gno * 16 + (n - 64)] = vv + L2b[n - 64];
    }
  }
}

// ---- pull-L2: rebuild LDS CSR, gather hw2, accumulate out ----
__global__ __launch_bounds__(256) void pull2_kernel(const unsigned short* __restrict__ hw2,
                                                    const int* __restrict__ binned,
                                                    const int* __restrict__ gcur,
                                                    float* __restrict__ out) {
  __shared__ int csr[BCAP];
  __shared__ int cnt[256];
  __shared__ int off[256];
  __shared__ int deg[256];
  __shared__ float ot[64][16];
  const int t = threadIdx.x, bkt = blockIdx.x;
  const int wid = t >> 6, lane = t & 63;

  int count = gcur[bkt];
  if (count > BCAP) count = BCAP;
  const int* edges = binned + (size_t)bkt * BCAP;

  cnt[t] = 0;
  __syncthreads();
  for (int i = t; i < count; i += 256) {
    int w = edges[i];
    atomicAdd(&cnt[((w >> 19) & 63) * 4 + ((w >> 17) & 3)], 1);
  }
  __syncthreads();
  off[t] = cnt[t];
  __syncthreads();
  for (int s = 1; s < 256; s <<= 1) {
    int v = (t >= s) ? off[t - s] : 0;
    __syncthreads();
    off[t] += v;
    __syncthreads();
  }
  int excl = off[t] - cnt[t];
  deg[t] = cnt[t];
  __syncthreads();
  off[t] = excl;
  cnt[t] = excl;
  __syncthreads();
  for (int i = t; i < count; i += 256) {
    int w = edges[i];
    int k = ((w >> 19) & 63) * 4 + ((w >> 17) & 3);
    int p = atomicAdd(&cnt[k], 1);
    csr[p] = w & 0x1FFFF;
  }
  __syncthreads();

  // gather: 4 lanes per edge-slot (16 slots), 8B (4 ch) per lane
  const int slot = lane >> 2, cpart = lane & 3;
  for (int ii = 0; ii < 16; ++ii) {
    int nloc = wid * 16 + ii;
    float acc[4] = {0.f, 0.f, 0.f, 0.f};
#pragma unroll
    for (int r = 0; r < 4; ++r) {
      int k = nloc * 4 + r;
      int beg = off[k], dg = deg[k];
      float w = 1.0f / (float)(dg > 1 ? dg : 1);
      for (int p0 = 0; p0 < dg; p0 += 16) {
        int j = p0 + slot;
        bool pr = j < dg;
        int s = pr ? csr[beg + j] : 0;
        uint2 u = *(const uint2*)(hw2 + (size_t)s * 64 + r * 16 + cpart * 4);
        float wp = pr ? w : 0.f;
        acc[0] = fmaf(wp, bf2f((unsigned short)(u.x & 0xffffu)), acc[0]);
        acc[1] = fmaf(wp, bf2f((unsigned short)(u.x >> 16)), acc[1]);
        acc[2] = fmaf(wp, bf2f((unsigned short)(u.y & 0xffffu)), acc[2]);
        acc[3] = fmaf(wp, bf2f((unsigned short)(u.y >> 16)), acc[3]);
      }
    }
#pragma unroll
    for (int m = 4; m <= 32; m <<= 1)
#pragma unroll
      for (int q = 0; q < 4; ++q) acc[q] += __shfl_xor(acc[q], m);
    if (slot == 0)
      *(float4*)&ot[nloc][cpart * 4] = make_float4(acc[0], acc[1], acc[2], acc[3]);
  }
  __syncthreads();

  int row = t >> 2, q = t & 3;
  int gn = bkt * 64 + row;
  if (gn < NN) {
    float4 o = *(float4*)(out + (size_t)gn * 16 + q * 4);
    float4 a = *(float4*)&ot[row][q * 4];
    o.x += a.x; o.y += a.y; o.z += a.z; o.w += a.w;
    *(float4*)(out + (size_t)gn * 16 + q * 4) = o;
  }
}

extern "C" void kernel_launch(void* const* d_in, const int* in_sizes, int n_in,
                              void* d_out, int out_size, void* d_ws, size_t ws_size,
                              hipStream_t stream) {
  const float* x   = (const float*)d_in[0];
  const int*   src = (const int*)d_in[1];
  const int*   dst = (const int*)d_in[2];
  const float* W1  = (const float*)d_in[3];
  const float* L1w = (const float*)d_in[4];
  const float* L1b = (const float*)d_in[5];
  const float* W2  = (const float*)d_in[6];
  const float* L2w = (const float*)d_in[7];
  const float* L2b = (const float*)d_in[8];
  float* out = (float*)d_out;

  char* p = (char*)d_ws;
  int* binned = (int*)p;                      p += (size_t)NBKT * BCAP * 4;   // 19.2 MB
  int* gcur   = (int*)p;                      p += 8192;
  unsigned short* hwcat = (unsigned short*)p; p += (size_t)NN * 256 * 2;      // 51.2 MB
  unsigned short* h = (unsigned short*)p;     p += (size_t)NN * 64 * 2;       // 12.8 MB
  unsigned short* hw2 = (unsigned short*)p;   p += (size_t)NN * 64 * 2;       // 12.8 MB
  unsigned short* BT1 = (unsigned short*)p;   p += 320 * 256 * 2;
  unsigned short* BT2 = (unsigned short*)p;   p += 80 * 64 * 2;
  if ((size_t)(p - (char*)d_ws) > ws_size) return;  // visible fail (poison stays)

  hipMemsetAsync(gcur, 0, NBKT * 4, stream);
  prep_w_kernel<<<(320 * 256 + 80 * 64 + 255) / 256, 256, 0, stream>>>(W1, L1w, W2, L2w, BT1, BT2);
  fused1_kernel<<<NG1 + NB, 512, 0, stream>>>(x, BT1, L1b, src, dst, gcur, binned, hwcat, h);
  pull1_kernel<<<NBKT, 256, 0, stream>>>(h, hwcat, binned, gcur, BT2, L2b, hw2, out);
  pull2_kernel<<<NBKT, 256, 0, stream>>>(hw2, binned, gcur, out);
}

// Round 13
// 229.655 us; speedup vs baseline: 2.1667x; 1.1479x over previous
//
#include <hip/hip_runtime.h>

// EntityClassify (R-GCN) — round 13.
// r12 post-mortem: 264us; pull1=130us top (VALUBusy 38%, Occ 35%, not BW-
// bound). Fixes: (a) kill f32 htile — slot-0 lanes fuse self+relu+bf16-pack
// straight into the swizzled A-tile (LDS 31.7->23.8KB, 6 blocks/CU);
// (b) unified per-node edge list, key=src*4+r (hwcat off = key*64, hw2 off =
// key*16): one ~32-edge loop instead of 4x ~8 (predication waste 35%->12%),
// winv[256] LDS table for per-rel 1/deg; (c) same for pull2 (19KB LDS).

constexpr int NN = 100000, RR = 4, EE = 800000;
constexpr int RE = RR * EE;
constexpr int NBKT = (NN + 63) / 64;      // 1563 buckets of 64 dst nodes
constexpr int BCAP = 3072;                // per-bucket capacity (λ≈2046, σ≈45)
constexpr int NG1 = (NN + 63) / 64;       // 1563 gemm1 tiles (M=64)
constexpr int CHUNK = 8192;
constexpr int NB = (RE + CHUNK - 1) / CHUNK;  // 391 bin blocks
constexpr int EPT = CHUNK / 512;          // 16 edges per thread

typedef short bf16x8 __attribute__((ext_vector_type(8)));
typedef float f32x4 __attribute__((ext_vector_type(4)));

__device__ inline unsigned short f2bf(float f) {
  unsigned u = __float_as_uint(f);
  u += 0x7FFF + ((u >> 16) & 1);
  return (unsigned short)(u >> 16);
}
__device__ inline float bf2f(unsigned short s) {
  return __uint_as_float(((unsigned)s) << 16);
}

// ---- weights -> bf16 [n][k]: BT1 [320][256], BT2 [80][64] ----
__global__ __launch_bounds__(256) void prep_w_kernel(const float* __restrict__ W1,
                                                     const float* __restrict__ L1w,
                                                     const float* __restrict__ W2,
                                                     const float* __restrict__ L2w,
                                                     unsigned short* __restrict__ BT1,
                                                     unsigned short* __restrict__ BT2) {
  int idx = blockIdx.x * 256 + threadIdx.x;
  if (idx < 320 * 256) {
    int n = idx >> 8, k = idx & 255;
    float v = (n < 256) ? W1[((size_t)((n >> 6) * 256 + k)) * 64 + (n & 63)]
                        : L1w[(size_t)k * 64 + (n - 256)];
    BT1[idx] = f2bf(v);
  } else {
    int j = idx - 320 * 256;
    if (j < 80 * 64) {
      int n = j >> 6, k = j & 63;
      float v = (n < 64) ? W2[((size_t)((n >> 4) * 64 + k)) * 16 + (n & 15)]
                         : L2w[(size_t)k * 16 + (n - 64)];
      BT2[j] = f2bf(v);
    }
  }
}

// ---- fused1: bin blocks (every 5th) ∥ gemm1 blocks ----
__global__ __launch_bounds__(512) void fused1_kernel(const float* __restrict__ x,
                                                     const unsigned short* __restrict__ BT1,
                                                     const float* __restrict__ L1b,
                                                     const int* __restrict__ src,
                                                     const int* __restrict__ dst,
                                                     int* __restrict__ gcur,
                                                     int* __restrict__ binned,
                                                     unsigned short* __restrict__ hwcat,
                                                     unsigned short* __restrict__ h) {
  __shared__ char lds[49152];
  const int bid = blockIdx.x;
  const int t = threadIdx.x;
  const bool is_bin = (bid % 5 == 0) && (bid / 5 < NB);

  if (is_bin) {
    int* hist = (int*)lds;          // [NBKT]
    int* base = hist + NBKT;        // [NBKT]
    for (int k = t; k < NBKT; k += 512) hist[k] = 0;
    __syncthreads();
    const int e0 = (bid / 5) * CHUNK + t;
    int dl[EPT], sl[EPT];
#pragma unroll
    for (int i = 0; i < EPT; ++i) {
      int fl = e0 + i * 512;
      dl[i] = -1;
      if (fl < RE) {
        dl[i] = dst[fl];
        sl[i] = src[fl];
        atomicAdd(&hist[dl[i] >> 6], 1);
      }
    }
    __syncthreads();
    for (int k = t; k < NBKT; k += 512) {
      int hv = hist[k];
      base[k] = hv ? atomicAdd(&gcur[k], hv) : 0;
      hist[k] = 0;
    }
    __syncthreads();
#pragma unroll
    for (int i = 0; i < EPT; ++i) {
      if (dl[i] < 0) continue;
      int fl = e0 + i * 512;
      int r = fl / EE;
      int b = dl[i] >> 6;
      int off = atomicAdd(&hist[b], 1);
      int p = base[b] + off;
      // entry: key = src*4+r (bits 0..18) | dstlo (bits 19..24)
      if (p < BCAP) binned[(size_t)b * BCAP + p] = (sl[i] << 2) | r | ((dl[i] & 63) << 19);
    }
    return;
  }

  // ---- gemm1 role: M-tile 64, N=320, K=256 ----
  int nbins = (bid + 4) / 5;
  if (nbins > NB) nbins = NB;
  const int m0 = (bid - nbins) * 64;
  char* Al = lds;                      // 8 KB
  char* Bl = lds + 64 * 64 * 2;        // 40 KB
  const int wid = t >> 6, lane = t & 63;
  const int wm = wid >> 2, wn = wid & 3;
  const int l15 = lane & 15, g = lane >> 4;

  f32x4 acc[2][5];
#pragma unroll
  for (int i = 0; i < 2; ++i)
#pragma unroll
    for (int j = 0; j < 5; ++j) acc[i][j] = (f32x4){0.f, 0.f, 0.f, 0.f};

  for (int kc = 0; kc < 4; ++kc) {
    if (kc) __syncthreads();
#pragma unroll
    for (int it = 0; it < 2; ++it) {
      int fl = t + 512 * it;
      int row = fl >> 4, kq = (fl & 15) * 4;
      int rg = m0 + row;
      float4 v = (rg < NN) ? *(const float4*)(x + (size_t)rg * 256 + kc * 64 + kq)
                           : make_float4(0.f, 0.f, 0.f, 0.f);
      ushort4 pck = {f2bf(v.x), f2bf(v.y), f2bf(v.z), f2bf(v.w)};
      int wb = ((row * 64 + kq) * 2) ^ ((row & 7) << 4);
      *(ushort4*)(Al + wb) = pck;
    }
#pragma unroll
    for (int it = 0; it < 5; ++it) {
      int fl = t + 512 * it;
      int n = fl >> 3, i8 = (fl & 7) * 8;
      uint4 u = *(const uint4*)(BT1 + (size_t)n * 256 + kc * 64 + i8);
      int wb = ((n * 64 + i8) * 2) ^ ((n & 7) << 4);
      *(uint4*)(Bl + wb) = u;
    }
    __syncthreads();
#pragma unroll
    for (int ks = 0; ks < 2; ++ks) {
      bf16x8 af[2], bfr[5];
#pragma unroll
      for (int mi = 0; mi < 2; ++mi) {
        int row = wm * 32 + mi * 16 + l15;
        int byte = ((row * 64 + ks * 32 + g * 8) * 2) ^ ((row & 7) << 4);
        af[mi] = *(const bf16x8*)(Al + byte);
      }
#pragma unroll
      for (int ni = 0; ni < 5; ++ni) {
        int n = wn * 80 + ni * 16 + l15;
        int byte = ((n * 64 + ks * 32 + g * 8) * 2) ^ ((n & 7) << 4);
        bfr[ni] = *(const bf16x8*)(Bl + byte);
      }
#pragma unroll
      for (int mi = 0; mi < 2; ++mi)
#pragma unroll
        for (int ni = 0; ni < 5; ++ni)
          acc[mi][ni] = __builtin_amdgcn_mfma_f32_16x16x32_bf16(af[mi], bfr[ni], acc[mi][ni], 0, 0, 0);
    }
  }
#pragma unroll
  for (int mi = 0; mi < 2; ++mi) {
    int rbase = m0 + wm * 32 + mi * 16 + 4 * g;
#pragma unroll
    for (int ni = 0; ni < 5; ++ni) {
      int n0 = wn * 80 + ni * 16;
      int n = n0 + l15;
#pragma unroll
      for (int e = 0; e < 4; ++e) {
        int row = rbase + e;
        if (row >= NN) continue;
        float v = acc[mi][ni][e];
        if (n0 < 256) hwcat[(size_t)row * 256 + n] = f2bf(v);
        else h[(size_t)row * 64 + (n - 256)] = f2bf(v + L1b[n - 256]);
      }
    }
  }
}

// ---- pull-L1 + gemm2: one block per bucket (64 nodes) ----
__global__ __launch_bounds__(256) void pull1_kernel(const unsigned short* __restrict__ h,
                                                    const unsigned short* __restrict__ hwcat,
                                                    const int* __restrict__ binned,
                                                    const int* __restrict__ gcur,
                                                    const unsigned short* __restrict__ BT2,
                                                    const float* __restrict__ L2b,
                                                    unsigned short* __restrict__ hw2,
                                                    float* __restrict__ out) {
  __shared__ int csr[BCAP];            // 12 KB; overlaid by Bl after gather
  __shared__ int cnt[256];
  __shared__ int off[256];
  __shared__ float winv[256];
  __shared__ int tot[64];
  __shared__ char Al[64 * 64 * 2];     // 8 KB bf16 A-tile (swizzled)
  const int t = threadIdx.x, bkt = blockIdx.x;
  const int wid = t >> 6, lane = t & 63;
  const int l15 = lane & 15, g = lane >> 4;

  int count = gcur[bkt];
  if (count > BCAP) count = BCAP;
  const int* edges = binned + (size_t)bkt * BCAP;

  // CSR build: histogram by (node,rel) -> scan -> winv/tot -> place
  cnt[t] = 0;
  __syncthreads();
  for (int i = t; i < count; i += 256) {
    int w = edges[i];
    atomicAdd(&cnt[((w >> 19) & 63) * 4 + (w & 3)], 1);
  }
  __syncthreads();
  off[t] = cnt[t];
  __syncthreads();
  for (int s = 1; s < 256; s <<= 1) {
    int v = (t >= s) ? off[t - s] : 0;
    __syncthreads();
    off[t] += v;
    __syncthreads();
  }
  int excl = off[t] - cnt[t];
  winv[t] = 1.0f / (float)(cnt[t] > 1 ? cnt[t] : 1);
  __syncthreads();
  off[t] = excl;
  cnt[t] = excl;                        // placement cursor
  __syncthreads();
  if (t < 64) tot[t] = ((t == 63) ? count : off[(t + 1) * 4]) - off[t * 4];
  __syncthreads();
  for (int i = t; i < count; i += 256) {
    int w = edges[i];
    int k = ((w >> 19) & 63) * 4 + (w & 3);
    int p = atomicAdd(&cnt[k], 1);
    csr[p] = w & 0x7FFFF;               // key = src*4+r
  }
  __syncthreads();

  // gather: wave wid handles nodes wid*16..+15; unified list, 8 slots x 16B
  const int slot = lane >> 3, cpart = lane & 7;
  for (int ii = 0; ii < 16; ++ii) {
    int nloc = wid * 16 + ii;
    int beg = off[nloc * 4];
    int total = tot[nloc];
    float acc[8] = {0.f, 0.f, 0.f, 0.f, 0.f, 0.f, 0.f, 0.f};
    for (int p0 = 0; p0 < total; p0 += 8) {
      int j = p0 + slot;
      bool pr = j < total;
      int key = pr ? csr[beg + j] : 0;
      float wv = pr ? winv[nloc * 4 + (key & 3)] : 0.f;
      uint4 u = *(const uint4*)(hwcat + (size_t)key * 64 + cpart * 8);
#pragma unroll
      for (int q = 0; q < 4; ++q) {
        unsigned uu = (&u.x)[q];
        acc[q * 2]     = fmaf(wv, bf2f((unsigned short)(uu & 0xffffu)), acc[q * 2]);
        acc[q * 2 + 1] = fmaf(wv, bf2f((unsigned short)(uu >> 16)), acc[q * 2 + 1]);
      }
    }
#pragma unroll
    for (int m = 8; m <= 32; m <<= 1)
#pragma unroll
      for (int q = 0; q < 8; ++q) acc[q] += __shfl_xor(acc[q], m);
    if (slot == 0) {  // lanes 0..7: self + relu + pack -> swizzled A-tile
      int gn = bkt * 64 + nloc;
      unsigned pk[4];
      uint4 hu = make_uint4(0, 0, 0, 0);
      if (gn < NN) hu = *(const uint4*)(h + (size_t)gn * 64 + cpart * 8);
#pragma unroll
      for (int q = 0; q < 4; ++q) {
        unsigned a = (&hu.x)[q];
        float v0 = acc[q * 2]     + bf2f((unsigned short)(a & 0xffffu));
        float v1 = acc[q * 2 + 1] + bf2f((unsigned short)(a >> 16));
        pk[q] = (unsigned)f2bf(fmaxf(v0, 0.f)) | ((unsigned)f2bf(fmaxf(v1, 0.f)) << 16);
      }
      int wb = ((nloc * 64 + cpart * 8) * 2) ^ ((nloc & 7) << 4);
      *(uint4*)(Al + wb) = make_uint4(pk[0], pk[1], pk[2], pk[3]);
    }
  }
  __syncthreads();

  // stage B over csr region: 80 x 64 bf16 = 640 uint4
  char* Bl = (char*)csr;
#pragma unroll
  for (int it = 0; it < 3; ++it) {
    int fl = t + 256 * it;
    if (fl < 640) {
      int n = fl >> 3, i8 = (fl & 7) * 8;
      uint4 u = *(const uint4*)(BT2 + (size_t)n * 64 + i8);
      int wb = ((n * 64 + i8) * 2) ^ ((n & 7) << 4);
      *(uint4*)(Bl + wb) = u;
    }
  }
  __syncthreads();

  // gemm2: wave wid -> rows wid*16..+15, N=80
  f32x4 acc2[5];
#pragma unroll
  for (int j = 0; j < 5; ++j) acc2[j] = (f32x4){0.f, 0.f, 0.f, 0.f};
#pragma unroll
  for (int ks = 0; ks < 2; ++ks) {
    int ra = wid * 16 + l15;
    int byte = ((ra * 64 + ks * 32 + g * 8) * 2) ^ ((ra & 7) << 4);
    bf16x8 af = *(const bf16x8*)(Al + byte);
#pragma unroll
    for (int ni = 0; ni < 5; ++ni) {
      int n = ni * 16 + l15;
      int nb = ((n * 64 + ks * 32 + g * 8) * 2) ^ ((n & 7) << 4);
      bf16x8 bfr = *(const bf16x8*)(Bl + nb);
      acc2[ni] = __builtin_amdgcn_mfma_f32_16x16x32_bf16(af, bfr, acc2[ni], 0, 0, 0);
    }
  }
  int rb = wid * 16 + 4 * g;
#pragma unroll
  for (int ni = 0; ni < 5; ++ni) {
    int n0 = ni * 16;
    int n = n0 + l15;
#pragma unroll
    for (int e = 0; e < 4; ++e) {
      int gno = bkt * 64 + rb + e;
      if (gno >= NN) continue;
      float vv = acc2[ni][e];
      if (n0 < 64) hw2[(size_t)gno * 64 + n] = f2bf(vv);
      else out[(size_t)gno * 16 + (n - 64)] = vv + L2b[n - 64];
    }
  }
}

// ---- pull-L2: rebuild LDS CSR (unified), gather hw2, accumulate out ----
__global__ __launch_bounds__(256) void pull2_kernel(const unsigned short* __restrict__ hw2,
                                                    const int* __restrict__ binned,
                                                    const int* __restrict__ gcur,
                                                    float* __restrict__ out) {
  __shared__ int csr[BCAP];
  __shared__ int cnt[256];
  __shared__ int off[256];
  __shared__ float winv[256];
  __shared__ int tot[64];
  __shared__ float ot[64][16];
  const int t = threadIdx.x, bkt = blockIdx.x;
  const int wid = t >> 6, lane = t & 63;

  int count = gcur[bkt];
  if (count > BCAP) count = BCAP;
  const int* edges = binned + (size_t)bkt * BCAP;

  cnt[t] = 0;
  __syncthreads();
  for (int i = t; i < count; i += 256) {
    int w = edges[i];
    atomicAdd(&cnt[((w >> 19) & 63) * 4 + (w & 3)], 1);
  }
  __syncthreads();
  off[t] = cnt[t];
  __syncthreads();
  for (int s = 1; s < 256; s <<= 1) {
    int v = (t >= s) ? off[t - s] : 0;
    __syncthreads();
    off[t] += v;
    __syncthreads();
  }
  int excl = off[t] - cnt[t];
  winv[t] = 1.0f / (float)(cnt[t] > 1 ? cnt[t] : 1);
  __syncthreads();
  off[t] = excl;
  cnt[t] = excl;
  __syncthreads();
  if (t < 64) tot[t] = ((t == 63) ? count : off[(t + 1) * 4]) - off[t * 4];
  __syncthreads();
  for (int i = t; i < count; i += 256) {
    int w = edges[i];
    int k = ((w >> 19) & 63) * 4 + (w & 3);
    int p = atomicAdd(&cnt[k], 1);
    csr[p] = w & 0x7FFFF;
  }
  __syncthreads();

  // gather: 16 slots x 4 cparts (8B); hw2 offset = key*16 + cpart*4
  const int slot = lane >> 2, cpart = lane & 3;
  for (int ii = 0; ii < 16; ++ii) {
    int nloc = wid * 16 + ii;
    int beg = off[nloc * 4];
    int total = tot[nloc];
    float acc[4] = {0.f, 0.f, 0.f, 0.f};
    for (int p0 = 0; p0 < total; p0 += 16) {
      int j = p0 + slot;
      bool pr = j < total;
      int key = pr ? csr[beg + j] : 0;
      float wv = pr ? winv[nloc * 4 + (key & 3)] : 0.f;
      uint2 u = *(const uint2*)(hw2 + (size_t)key * 16 + cpart * 4);
      acc[0] = fmaf(wv, bf2f((unsigned short)(u.x & 0xffffu)), acc[0]);
      acc[1] = fmaf(wv, bf2f((unsigned short)(u.x >> 16)), acc[1]);
      acc[2] = fmaf(wv, bf2f((unsigned short)(u.y & 0xffffu)), acc[2]);
      acc[3] = fmaf(wv, bf2f((unsigned short)(u.y >> 16)), acc[3]);
    }
#pragma unroll
    for (int m = 4; m <= 32; m <<= 1)
#pragma unroll
      for (int q = 0; q < 4; ++q) acc[q] += __shfl_xor(acc[q], m);
    if (slot == 0)
      *(float4*)&ot[nloc][cpart * 4] = make_float4(acc[0], acc[1], acc[2], acc[3]);
  }
  __syncthreads();

  int row = t >> 2, q = t & 3;
  int gn = bkt * 64 + row;
  if (gn < NN) {
    float4 o = *(float4*)(out + (size_t)gn * 16 + q * 4);
    float4 a = *(float4*)&ot[row][q * 4];
    o.x += a.x; o.y += a.y; o.z += a.z; o.w += a.w;
    *(float4*)(out + (size_t)gn * 16 + q * 4) = o;
  }
}

extern "C" void kernel_launch(void* const* d_in, const int* in_sizes, int n_in,
                              void* d_out, int out_size, void* d_ws, size_t ws_size,
                              hipStream_t stream) {
  const float* x   = (const float*)d_in[0];
  const int*   src = (const int*)d_in[1];
  const int*   dst = (const int*)d_in[2];
  const float* W1  = (const float*)d_in[3];
  const float* L1w = (const float*)d_in[4];
  const float* L1b = (const float*)d_in[5];
  const float* W2  = (const float*)d_in[6];
  const float* L2w = (const float*)d_in[7];
  const float* L2b = (const float*)d_in[8];
  float* out = (float*)d_out;

  char* p = (char*)d_ws;
  int* binned = (int*)p;                      p += (size_t)NBKT * BCAP * 4;   // 19.2 MB
  int* gcur   = (int*)p;                      p += 8192;
  unsigned short* hwcat = (unsigned short*)p; p += (size_t)NN * 256 * 2;      // 51.2 MB
  unsigned short* h = (unsigned short*)p;     p += (size_t)NN * 64 * 2;       // 12.8 MB
  unsigned short* hw2 = (unsigned short*)p;   p += (size_t)NN * 64 * 2;       // 12.8 MB
  unsigned short* BT1 = (unsigned short*)p;   p += 320 * 256 * 2;
  unsigned short* BT2 = (unsigned short*)p;   p += 80 * 64 * 2;
  if ((size_t)(p - (char*)d_ws) > ws_size) return;  // visible fail (poison stays)

  hipMemsetAsync(gcur, 0, NBKT * 4, stream);
  prep_w_kernel<<<(320 * 256 + 80 * 64 + 255) / 256, 256, 0, stream>>>(W1, L1w, W2, L2w, BT1, BT2);
  fused1_kernel<<<NG1 + NB, 512, 0, stream>>>(x, BT1, L1b, src, dst, gcur, binned, hwcat, h);
  pull1_kernel<<<NBKT, 256, 0, stream>>>(h, hwcat, binned, gcur, BT2, L2b, hw2, out);
  pull2_kernel<<<NBKT, 256, 0, stream>>>(hw2, binned, gcur, out);
}